// Round 6
// baseline (828.212 us; speedup 1.0000x reference)
//
#include <hip/hip_runtime.h>

#define NN 8192
#define EE 262144
#define TT 256
#define HH 2048
#define OO 1024
#define LL 128
#define NW 10

typedef __bf16 bf16_t;
typedef __bf16 bf16x8_t __attribute__((ext_vector_type(8)));
typedef float f32x4_t __attribute__((ext_vector_type(4)));

__device__ __forceinline__ void async16(void* lds, const void* g) {
  __builtin_amdgcn_global_load_lds(
      (const __attribute__((address_space(1))) void*)g,
      (__attribute__((address_space(3))) void*)lds, 16, 0, 0);
}

// Activations: 256-col tiled layout. elem(row,col) at (col>>8)*NN*256 + row*256 + (col&255).
// Empirically validated on this box (r8): workgroup -> XCD assignment is blockIdx % 8.
//
// Packed-B layout (for gemm256, weights w*_0..w2_2): for Bt[n][k] (N x K, n-major),
// block blk = (n>>8)*(K>>6) + (k>>6) of 16384 elems; within block, group
// g = (((nh*4+wn)*2+j)*2+ks) of 512 elems (nh=(n>>7)&1, wn=(n>>5)&3, j=(n>>4)&1,
// ks=(k&63)>>5); within group, lane = ((k>>3)&3)*16 + (n&15), elems e=k&7.
// A wave's B-fragment load is then ONE coalesced 1KB global_load_dwordx4 per (nh,j,ks).

__device__ __forceinline__ size_t packed_off(int ng, int kg0, int K) {
  size_t blk = (size_t)(ng >> 8) * (K >> 6) + (kg0 >> 6);
  int g = ((((ng >> 7) & 1) * 4 + ((ng >> 5) & 3)) * 2 + ((ng >> 4) & 1)) * 2 +
          ((kg0 & 63) >> 5);
  int lane_ = (((kg0 >> 3) & 3) << 4) + (ng & 15);
  return blk * 16384 + (size_t)g * 512 + (size_t)lane_ * 8;
}

// ---------------- CSR build (dst-major) ----------------
__global__ __launch_bounds__(256) void count_deg_kernel(const int* __restrict__ dst,
                                                        int* __restrict__ deg) {
  int e = blockIdx.x * 256 + threadIdx.x;
  if (e < EE) atomicAdd(&deg[dst[e]], 1);
}

__global__ __launch_bounds__(1024) void scan_kernel(const int* __restrict__ deg,
                                                    int* __restrict__ rs) {
  __shared__ int s[1024];
  int t = threadIdx.x;
  int pre[8];
  int sum = 0;
#pragma unroll
  for (int j = 0; j < 8; ++j) { pre[j] = sum; sum += deg[t * 8 + j]; }
  s[t] = sum;
  __syncthreads();
  for (int off = 1; off < 1024; off <<= 1) {
    int add = (t >= off) ? s[t - off] : 0;
    __syncthreads();
    s[t] += add;
    __syncthreads();
  }
  int base = (t == 0) ? 0 : s[t - 1];
#pragma unroll
  for (int j = 0; j < 8; ++j) rs[t * 8 + j] = base + pre[j];
  if (t == 1023) rs[8192] = s[1023];
}

__global__ __launch_bounds__(256) void fill_csr_kernel(const int* __restrict__ src,
                                                       const int* __restrict__ dst,
                                                       const int* __restrict__ rs,
                                                       int* __restrict__ cur,
                                                       int* __restrict__ csr) {
  int e = blockIdx.x * 256 + threadIdx.x;
  if (e >= EE) return;
  int d = dst[e];
  int p = atomicAdd(&cur[d], 1);
  csr[rs[d] + p] = src[e];
}

// ---------------- merged prep: all 9 weight transposes + x0 cast ----------------
struct WTab {
  const float* src[NW];
  int K[NW];
  int N[NW];
  int packed[NW];
  long long dstOff[NW];
  int tileStart[NW + 1];
  const float* x0;
  bf16_t* castDst;
  int castStart;
};

__global__ __launch_bounds__(256) void prep_all_kernel(WTab tab, bf16_t* __restrict__ WT) {
  int b = blockIdx.x;
  int t = threadIdx.x;
  if (b >= tab.castStart) {
    int i = (b - tab.castStart) * 256 + t;
    f32x4_t a = ((const f32x4_t*)tab.x0)[i * 2];
    f32x4_t bb = ((const f32x4_t*)tab.x0)[i * 2 + 1];
    bf16x8_t o;
#pragma unroll
    for (int j = 0; j < 4; ++j) { o[j] = (bf16_t)a[j]; o[4 + j] = (bf16_t)bb[j]; }
    ((bf16x8_t*)tab.castDst)[i] = o;
    return;
  }
  int wi = 0;
#pragma unroll
  for (int k = 1; k < NW; ++k)
    if (b >= tab.tileStart[k]) wi = k;
  int tt = b - tab.tileStart[wi];
  int K = tab.K[wi], N = tab.N[wi];
  int ntn = N >> 6;
  int n0 = (tt % ntn) * 64, k0 = (tt / ntn) * 64;
  const float* in = tab.src[wi];
  bf16_t* out = WT + tab.dstOff[wi];
  int packed = tab.packed[wi];

  __shared__ float tile[64][65];
  for (int c = t; c < 1024; c += 256) {
    int r = c >> 4, col = (c & 15) * 4;
    f32x4_t v = *(const f32x4_t*)&in[(size_t)(k0 + r) * N + n0 + col];
#pragma unroll
    for (int j = 0; j < 4; ++j) tile[r][col + j] = v[j];
  }
  __syncthreads();
  for (int c = t; c < 512; c += 256) {
    int r = c >> 3, col = (c & 7) * 8;
    bf16x8_t v;
#pragma unroll
    for (int j = 0; j < 8; ++j) v[j] = (bf16_t)tile[col + j][r];
    if (packed) {
      *(bf16x8_t*)&out[packed_off(n0 + r, k0 + col, K)] = v;
    } else {
      *(bf16x8_t*)&out[(size_t)(n0 + r) * K + k0 + col] = v;
    }
  }
}

// ---------------- standalone transpose+cast (fallback path) ----------------
__global__ __launch_bounds__(256) void transpose_cast_kernel(const float* __restrict__ in,
                                                             bf16_t* __restrict__ out,
                                                             int K, int N, int packed) {
  __shared__ float tile[64][65];
  int n0 = blockIdx.x * 64, k0 = blockIdx.y * 64;
  int t = threadIdx.x;
  for (int c = t; c < 1024; c += 256) {
    int r = c >> 4, col = (c & 15) * 4;
    f32x4_t v = *(const f32x4_t*)&in[(size_t)(k0 + r) * N + n0 + col];
#pragma unroll
    for (int j = 0; j < 4; ++j) tile[r][col + j] = v[j];
  }
  __syncthreads();
  for (int c = t; c < 512; c += 256) {
    int r = c >> 3, col = (c & 7) * 8;
    bf16x8_t v;
#pragma unroll
    for (int j = 0; j < 8; ++j) v[j] = (bf16_t)tile[col + j][r];
    if (packed) {
      *(bf16x8_t*)&out[packed_off(n0 + r, k0 + col, K)] = v;
    } else {
      *(bf16x8_t*)&out[(size_t)(n0 + r) * K + k0 + col] = v;
    }
  }
}

__global__ __launch_bounds__(256) void cast_kernel(const float* __restrict__ in,
                                                   bf16_t* __restrict__ out) {
  int i = blockIdx.x * 256 + threadIdx.x;
  f32x4_t a = ((const f32x4_t*)in)[i * 2];
  f32x4_t b = ((const f32x4_t*)in)[i * 2 + 1];
  bf16x8_t o;
#pragma unroll
  for (int j = 0; j < 4; ++j) { o[j] = (bf16_t)a[j]; o[4 + j] = (bf16_t)b[j]; }
  ((bf16x8_t*)out)[i] = o;
}

// ------- layer-0 aggregation, d=256 -------
__global__ __launch_bounds__(64) void agg0_kernel(const bf16_t* __restrict__ x,
                                                  bf16_t* __restrict__ out,
                                                  const int* __restrict__ rs,
                                                  const int* __restrict__ csr) {
  int t = threadIdx.x;
  int node = blockIdx.x * 2 + (t >> 5);
  int c = t & 31;
  const bf16x8_t* xv = (const bf16x8_t*)x;
  bf16x8_t self = xv[(size_t)node * 32 + c];
  float acc[8];
#pragma unroll
  for (int j = 0; j < 8; ++j) acc[j] = (float)self[j];
  int e0 = rs[node], e1 = rs[node + 1];
  int e = e0;
  for (; e + 4 <= e1; e += 4) {
    int s0 = csr[e], s1 = csr[e + 1], s2 = csr[e + 2], s3 = csr[e + 3];
    bf16x8_t v0 = xv[(size_t)s0 * 32 + c];
    bf16x8_t v1 = xv[(size_t)s1 * 32 + c];
    bf16x8_t v2 = xv[(size_t)s2 * 32 + c];
    bf16x8_t v3 = xv[(size_t)s3 * 32 + c];
#pragma unroll
    for (int j = 0; j < 8; ++j)
      acc[j] += (float)v0[j] + (float)v1[j] + (float)v2[j] + (float)v3[j];
  }
  for (; e < e1; ++e) {
    bf16x8_t v = xv[(size_t)csr[e] * 32 + c];
#pragma unroll
    for (int j = 0; j < 8; ++j) acc[j] += (float)v[j];
  }
  bf16x8_t o;
#pragma unroll
  for (int j = 0; j < 8; ++j) o[j] = (bf16_t)acc[j];
  ((bf16x8_t*)out)[(size_t)node * 32 + c] = o;
}

// ------- aggregation over tiled activations, XCD-pinned tiles (validated r8) -------
__global__ __launch_bounds__(256) void agg_tiled_kernel(const bf16_t* __restrict__ x,
                                                        bf16_t* __restrict__ out,
                                                        const int* __restrict__ rs,
                                                        const int* __restrict__ csr,
                                                        const float* __restrict__ bias,
                                                        int relu, int tmask, int tshift) {
  int t = threadIdx.x;
  int tile = blockIdx.x & tmask;
  int ng = blockIdx.x >> tshift;
  int node = ng * 8 + (t >> 5);
  int c = t & 31;
  size_t tb = (size_t)tile * (NN * 32);
  const bf16x8_t* xv = (const bf16x8_t*)x + tb;
  bf16x8_t self = xv[node * 32 + c];
  float acc[8];
#pragma unroll
  for (int j = 0; j < 8; ++j) acc[j] = (float)self[j];
  int e0 = rs[node], e1 = rs[node + 1];
  int e = e0;
  for (; e + 4 <= e1; e += 4) {
    int s0 = csr[e], s1 = csr[e + 1], s2 = csr[e + 2], s3 = csr[e + 3];
    bf16x8_t v0 = xv[s0 * 32 + c];
    bf16x8_t v1 = xv[s1 * 32 + c];
    bf16x8_t v2 = xv[s2 * 32 + c];
    bf16x8_t v3 = xv[s3 * 32 + c];
#pragma unroll
    for (int j = 0; j < 8; ++j)
      acc[j] += (float)v0[j] + (float)v1[j] + (float)v2[j] + (float)v3[j];
  }
  for (; e < e1; ++e) {
    bf16x8_t v = xv[csr[e] * 32 + c];
#pragma unroll
    for (int j = 0; j < 8; ++j) acc[j] += (float)v[j];
  }
  if (bias) {
    const float* bp = bias + tile * 256 + c * 8;
    f32x4_t b0 = *(const f32x4_t*)bp;
    f32x4_t b1 = *(const f32x4_t*)(bp + 4);
#pragma unroll
    for (int j = 0; j < 4; ++j) { acc[j] += b0[j]; acc[4 + j] += b1[j]; }
  }
  if (relu) {
#pragma unroll
    for (int j = 0; j < 8; ++j) acc[j] = fmaxf(acc[j], 0.f);
  }
  bf16x8_t o;
#pragma unroll
  for (int j = 0; j < 8; ++j) o[j] = (bf16_t)acc[j];
  ((bf16x8_t*)out + tb)[node * 32 + c] = o;
}

// ------- OLD GEMM (128x128 tile): kept for N=1024 GEMMs and the heads GEMM -------
template <int CMODE>
__global__ __launch_bounds__(256, 2) void gemm_bt_kernel(
    const bf16_t* __restrict__ A, const bf16_t* __restrict__ Bt,
    const float* __restrict__ bias, const float* __restrict__ biasB,
    void* __restrict__ Cv, int N, int K, int relu, int nbxShift) {
  __shared__ __align__(16) bf16_t lA[128 * 32];
  __shared__ __align__(16) bf16_t lB[128 * 32];
  const int tid = threadIdx.x;
  const int lane = tid & 63;
  const int wave = tid >> 6;
  const int wm64 = (wave & 1) * 64;
  const int wn64 = (wave >> 1) * 64;
  const int row16 = lane & 15;
  const int quad = lane >> 4;

  const int bid = blockIdx.x;
  const int xcd = bid & 7;
  const int rank = bid >> 3;
  const int bn = rank & ((1 << nbxShift) - 1);
  const int mPer = gridDim.x >> (3 + nbxShift);
  const int bm = xcd * mPer + (rank >> nbxShift);
  const size_t m0 = (size_t)bm * 128;
  const size_t n0 = (size_t)bn * 128;

  f32x4_t acc[4][4];
#pragma unroll
  for (int i = 0; i < 4; ++i)
#pragma unroll
    for (int j = 0; j < 4; ++j)
#pragma unroll
      for (int r = 0; r < 4; ++r) acc[i][j][r] = 0.f;

  const bf16_t* Bbase = Bt + n0 * K;
  const int r0 = tid >> 2;
  const int r1 = (tid + 256) >> 2;
  const int kc = (tid & 3) * 8;

  for (int kt = 0; kt < K; kt += 32) {
    const bf16_t* Ab = A + ((size_t)(kt >> 8)) * (NN * 256) + (kt & 255) + kc;
    async16(&lA[tid * 8], Ab + (m0 + r0) * 256);
    async16(&lA[(tid + 256) * 8], Ab + (m0 + r1) * 256);
    async16(&lB[tid * 8], Bbase + (size_t)r0 * K + kt + kc);
    async16(&lB[(tid + 256) * 8], Bbase + (size_t)r1 * K + kt + kc);
    __syncthreads();
    bf16x8_t af[4], bfr[4];
#pragma unroll
    for (int i = 0; i < 4; ++i)
      af[i] = *(const bf16x8_t*)&lA[(wm64 + i * 16 + row16) * 32 + quad * 8];
#pragma unroll
    for (int i = 0; i < 4; ++i)
      bfr[i] = *(const bf16x8_t*)&lB[(wn64 + i * 16 + row16) * 32 + quad * 8];
#pragma unroll
    for (int i = 0; i < 4; ++i)
#pragma unroll
      for (int j = 0; j < 4; ++j)
        acc[i][j] = __builtin_amdgcn_mfma_f32_16x16x32_bf16(af[i], bfr[j], acc[i][j], 0, 0, 0);
    __syncthreads();
  }

  // C/D layout: col = lane&15, row = quad*4 + reg  [verified m89/m91]
#pragma unroll
  for (int i = 0; i < 4; ++i) {
    size_t row = m0 + wm64 + i * 16 + quad * 4;
#pragma unroll
    for (int j = 0; j < 4; ++j) {
      int col = (int)n0 + wn64 + j * 16 + row16;
      if (CMODE == 0) {
        float b = bias ? bias[col] : 0.f;
        size_t cb = ((size_t)(col >> 8)) * (NN * 256) + (col & 255);
#pragma unroll
        for (int r = 0; r < 4; ++r) {
          float o = acc[i][j][r] + b;
          if (relu) o = fmaxf(o, 0.f);
          ((bf16_t*)Cv)[cb + (row + r) * 256] = (bf16_t)o;
        }
      } else {
        int sel = col >> 7;
        int c2 = col & 127;
        float b = sel ? biasB[c2] : bias[c2];
        float* dstp = (float*)Cv + (size_t)(1 + sel) * NN * LL + c2;
#pragma unroll
        for (int r = 0; r < 4; ++r) {
          dstp[(row + r) * LL] = acc[i][j][r] + b;
        }
      }
    }
  }
}

// ------- NEW GEMM: 256x256 tile, BK=64, 8-wave, B-from-L2-registers, 2-phase/K-tile ----
// B is a packed L2-resident weight: each wave loads its 8 B-fragments per K-tile as
// coalesced global_load_dwordx4 (1KB each) directly into registers -- no B LDS staging,
// no B ds_reads. Only A goes through LDS (double-buffered, 64KB total). K-tile is 2
// phases x {vmcnt; bar; 8 A-ds_reads; issue next-tile B-loads/A-stage; 32 MFMA}.
// VMEM FIFO per tile X: ph0 issues [B(X+1) x8, A0(X+1) x2], ph1 issues [A1(X+1) x2].
//  - ph0 entry outstanding = [B(X)8, A0(X)2, A1(X)2] = 12 -> VMC(2) drains B(X)+A0(X)
//    (covers both the B-register RAW and the A0 LDS RAW); BAR publishes to all waves.
//  - ph1 entry outstanding = [A1(X)2, B(X+1)8, A0(X+1)2] = 12 -> VMC(10) drains A1(X).
// Robust to intra-group reorder: drains are prefix-drains of whole groups; group
// boundaries pinned by the memory-clobber asm (loads cannot cross asm "memory").
// WAR on A slots with only 2 barriers/tile: lgkm is FIFO, so the compiler's wait before
// phase-p MFMA (covering the newest ds_reads) drains all older reads; barrier arrival
// therefore implies every wave's reads of the slot being restaged are COMPLETE.
// B regs double-buffered with static names via 2x loop unroll (rule #20).
// LDS A swizzle elem^=(row&7)<<3, inverse pre-applied to global source (rule #21).
__global__ __launch_bounds__(512, 2) void gemm256_kernel(
    const bf16_t* __restrict__ A, const bf16_t* __restrict__ Bt,
    const float* __restrict__ bias, bf16_t* __restrict__ C,
    int N, int K, int relu, int nbxShift) {
  __shared__ __align__(16) bf16_t lA[2][256 * 64];

  const int t = threadIdx.x;
  const int lane = t & 63;
  const int wave = t >> 6;
  const int wm = wave >> 2;  // 0..1
  const int wn = wave & 3;   // 0..3
  const int row16 = lane & 15;
  const int quad = lane >> 4;
  const int sx = (row16 & 7) << 3;  // read-side swizzle XOR (elements)

  const int r0 = t >> 3;
  const int cs = ((t & 7) * 8) ^ ((r0 & 7) << 3);  // pre-swizzled source column

  const int bid = blockIdx.x;
  const int xcd = bid & 7;
  const int rank = bid >> 3;
  const int bn = rank & ((1 << nbxShift) - 1);
  const int mPer = gridDim.x >> (3 + nbxShift);
  const int bm = xcd * mPer + (rank >> nbxShift);
  const size_t m0 = (size_t)bm * 256;
  const size_t n0 = (size_t)bn * 256;
  const int NT = K >> 6;

  f32x4_t acc[4][4][2];
#pragma unroll
  for (int Q = 0; Q < 4; ++Q)
#pragma unroll
    for (int i = 0; i < 4; ++i)
#pragma unroll
      for (int j = 0; j < 2; ++j)
#pragma unroll
        for (int r = 0; r < 4; ++r) acc[Q][i][j][r] = 0.f;

  bf16x8_t af[4][2], bfE[2][2][2], bfO[2][2][2];

#define LOAD_A(cc, mh)                                                              \
  _Pragma("unroll") for (int i = 0; i < 4; ++i)                                     \
  _Pragma("unroll") for (int ks = 0; ks < 2; ++ks) {                                \
    int row_ = (mh)*128 + wm * 64 + i * 16 + row16;                                 \
    af[i][ks] = *(const bf16x8_t*)&lA[cc][row_ * 64 + ((ks * 32 + quad * 8) ^ sx)]; \
  }

#define BLOAD(BF, U)                                                                \
  {                                                                                 \
    int u_ = (U);                                                                   \
    int us_ = u_ < NT ? u_ : NT - 1;                                                \
    const bf16x8_t* bp_ =                                                           \
        (const bf16x8_t*)(Bt + ((size_t)bn * NT + us_) * 16384) + lane;             \
    _Pragma("unroll") for (int nh = 0; nh < 2; ++nh)                                \
    _Pragma("unroll") for (int j = 0; j < 2; ++j)                                   \
    _Pragma("unroll") for (int ks = 0; ks < 2; ++ks)                                \
        BF[nh][j][ks] = bp_[((((nh)*4 + wn) * 2 + j) * 2 + ks) * 64];               \
  }

#define STAGE_A256(U, mh)                                                            \
  {                                                                                  \
    int u_ = (U);                                                                    \
    int us_ = u_ < NT ? u_ : NT - 1;                                                 \
    int kt_ = us_ << 6;                                                              \
    const bf16_t* g_ = A + (size_t)(kt_ >> 8) * (NN * 256) + (m0 + (mh)*128) * 256 + \
                       (kt_ & 255) + cs;                                             \
    bf16_t* l_ = &lA[u_ & 1][(mh)*8192];                                             \
    async16(l_ + (size_t)t * 8, g_ + (size_t)r0 * 256);                              \
    async16(l_ + (size_t)(t + 512) * 8, g_ + (size_t)(r0 + 64) * 256);               \
  }

#define MFMA_PH(mh, BF)                                                              \
  __builtin_amdgcn_s_setprio(1);                                                     \
  _Pragma("unroll") for (int nh = 0; nh < 2; ++nh)                                   \
  _Pragma("unroll") for (int i = 0; i < 4; ++i)                                      \
  _Pragma("unroll") for (int j = 0; j < 2; ++j)                                      \
  _Pragma("unroll") for (int ks = 0; ks < 2; ++ks)                                   \
      acc[(mh)*2 + nh][i][j] = __builtin_amdgcn_mfma_f32_16x16x32_bf16(              \
          af[i][ks], BF[nh][j][ks], acc[(mh)*2 + nh][i][j], 0, 0, 0);                \
  __builtin_amdgcn_s_setprio(0);

#define BARS                                                               \
  do {                                                                     \
    __builtin_amdgcn_sched_barrier(0);                                     \
    asm volatile("s_barrier" ::: "memory");                                \
    __builtin_amdgcn_sched_barrier(0);                                     \
  } while (0)

#define VMC(n_)                                                            \
  do {                                                                     \
    asm volatile("s_waitcnt vmcnt(" #n_ ")" ::: "memory");                 \
    __builtin_amdgcn_sched_barrier(0);                                     \
  } while (0)

#define TILE(X, cc, CUR, NXT)                                              \
  {                                                                        \
    /* ph0 */                                                              \
    VMC(2);                                                                \
    BARS;                                                                  \
    LOAD_A(cc, 0);                                                         \
    BLOAD(NXT, (X) + 1);                                                   \
    STAGE_A256((X) + 1, 0);                                                \
    MFMA_PH(0, CUR);                                                       \
    /* ph1 */                                                              \
    VMC(10);                                                               \
    BARS;                                                                  \
    LOAD_A(cc, 1);                                                         \
    STAGE_A256((X) + 1, 1);                                                \
    MFMA_PH(1, CUR);                                                       \
  }

  // Prologue: stage A(0) (both halves) + load B(0); full drain once (outside loop).
  STAGE_A256(0, 0); STAGE_A256(0, 1);
  BLOAD(bfE, 0);
  VMC(0);
  BARS;

  for (int T = 0; T < NT; T += 2) {
    TILE(T, 0, bfE, bfO);
    TILE(T + 1, 1, bfO, bfE);
  }
  asm volatile("s_waitcnt vmcnt(0)" ::: "memory");

  // Epilogue: C/D layout col = lane&15, row = quad*4 + reg [verified m89/m91]
#pragma unroll
  for (int Q = 0; Q < 4; ++Q) {
    const int mh = Q >> 1, nh = Q & 1;
#pragma unroll
    for (int i = 0; i < 4; ++i) {
      size_t row = m0 + mh * 128 + wm * 64 + i * 16 + quad * 4;
#pragma unroll
      for (int j = 0; j < 2; ++j) {
        int col = (int)n0 + nh * 128 + wn * 32 + j * 16 + row16;
        float b = bias ? bias[col] : 0.f;
        size_t cb = ((size_t)(col >> 8)) * (NN * 256) + (col & 255);
#pragma unroll
        for (int r = 0; r < 4; ++r) {
          float o = acc[Q][i][j][r] + b;
          if (relu) o = fmaxf(o, 0.f);
          C[cb + (row + r) * 256] = (bf16_t)o;
        }
      }
    }
  }
#undef LOAD_A
#undef BLOAD
#undef STAGE_A256
#undef MFMA_PH
#undef BARS
#undef VMC
#undef TILE
}

// ---------------- z = mean + var*eps (f32) ----------------
__global__ __launch_bounds__(256) void reparam_kernel(const float* __restrict__ mean,
                                                      const float* __restrict__ var,
                                                      const float* __restrict__ eps,
                                                      float* __restrict__ z) {
  int i = blockIdx.x * 256 + threadIdx.x;
  f32x4_t m = ((const f32x4_t*)mean)[i];
  f32x4_t v = ((const f32x4_t*)var)[i];
  f32x4_t e = ((const f32x4_t*)eps)[i];
  f32x4_t o;
#pragma unroll
  for (int j = 0; j < 4; ++j) o[j] = m[j] + v[j] * e[j];
  ((f32x4_t*)z)[i] = o;
}

extern "C" void kernel_launch(void* const* d_in, const int* in_sizes, int n_in,
                              void* d_out, int out_size, void* d_ws, size_t ws_size,
                              hipStream_t stream) {
  (void)in_sizes; (void)n_in; (void)out_size;
  const float* x0 = (const float*)d_in[0];
  const int* ei = (const int*)d_in[1];
  const int* src = ei;
  const int* dst = ei + EE;
  const float* w1[4] = {(const float*)d_in[2], (const float*)d_in[6],
                        (const float*)d_in[10], (const float*)d_in[14]};
  const float* b1[4] = {(const float*)d_in[3], (const float*)d_in[7],
                        (const float*)d_in[11], (const float*)d_in[15]};
  const float* w2[4] = {(const float*)d_in[4], (const float*)d_in[8],
                        (const float*)d_in[12], (const float*)d_in[16]};
  const float* b2[4] = {(const float*)d_in[5], (const float*)d_in[9],
                        (const float*)d_in[13], (const float*)d_in[17]};
  const float* wm = (const float*)d_in[18];
  const float* bm = (const float*)d_in[19];
  const float* wv = (const float*)d_in[20];
  const float* bv = (const float*)d_in[21];
  const float* eps = (const float*)d_in[22];
  float* out = (float*)d_out;

  char* ws = (char*)d_ws;
  bf16_t* B0 = (bf16_t*)(ws);
  bf16_t* B1 = (bf16_t*)(ws + 33554432);
  bf16_t* WT = (bf16_t*)(ws + 67108864);

  // Per-weight WT slot offsets (bf16 elems), order: w1_0,w2_0,w1_1,w2_1,w1_2,w2_2,w1_3,w2_3,wm,wv
  const long long soff[NW] = {0LL, 524288LL, 4718592LL, 8912896LL, 13107200LL,
                              17301504LL, 21495808LL, 23592960LL, 24641536LL, 24772608LL};
  const size_t wtBytesFull = 24903680ULL * 2ULL;          // 49.8 MB
  const size_t needFull = 67108864ULL + wtBytesFull + 2097152ULL;
  bool full = ws_size >= needFull;

  size_t csrBase = full ? (67108864ULL + wtBytesFull) : 75497472ULL;
  int* deg = (int*)(ws + csrBase);
  int* cur = deg + 8192;
  int* rs = deg + 16384;
  int* csr = deg + 16384 + 8200;

  auto AGG = [&](const bf16_t* in, bf16_t* outp, int d, const float* bias, int relu) {
    int ntiles = d >> 8;
    int tshift = (ntiles == 8) ? 3 : 2;
    agg_tiled_kernel<<<(NN / 8) * ntiles, 256, 0, stream>>>(in, outp, rs, csr, bias, relu,
                                                            ntiles - 1, tshift);
  };

  if (full) {
    // ---- merged prep: all transposes + x0 cast in one dispatch ----
    WTab tab;
    const float* srcs[NW] = {w1[0], w2[0], w1[1], w2[1], w1[2], w2[2], w1[3], w2[3], wm, wv};
    const int Ks[NW] = {TT, HH, HH, HH, HH, HH, HH, OO, OO, OO};
    const int Ns[NW] = {HH, HH, HH, HH, HH, HH, OO, OO, LL, LL};
    const int Ps[NW] = {1, 1, 1, 1, 1, 1, 0, 0, 0, 0};  // packed-B for gemm256 weights
    int cum = 0;
    for (int i = 0; i < NW; ++i) {
      tab.src[i] = srcs[i];
      tab.K[i] = Ks[i];
      tab.N[i] = Ns[i];
      tab.packed[i] = Ps[i];
      tab.dstOff[i] = soff[i];
      tab.tileStart[i] = cum;
      cum += (Ns[i] >> 6) * (Ks[i] >> 6);
    }
    tab.tileStart[NW] = cum;
    tab.castStart = cum;
    tab.x0 = x0;
    tab.castDst = B0;
    int totalBlocks = cum + (NN * TT / 8) / 256;
    prep_all_kernel<<<totalBlocks, 256, 0, stream>>>(tab, WT);

    hipMemsetAsync(deg, 0, 2 * 8192 * sizeof(int), stream);
    count_deg_kernel<<<EE / 256, 256, 0, stream>>>(dst, deg);
    scan_kernel<<<1, 1024, 0, stream>>>(deg, rs);
    fill_csr_kernel<<<EE / 256, 256, 0, stream>>>(src, dst, rs, cur, csr);

    // N=2048 GEMMs -> new 256^2 kernel (grid 256 = 1 block/CU, nbxShift=3)
    auto G2 = [&](const bf16_t* Ain, int wi, const float* bias, bf16_t* Cout, int K, int relu) {
      gemm256_kernel<<<8 * (NN / 256), 512, 0, stream>>>(Ain, WT + soff[wi], bias, Cout,
                                                         HH, K, relu, 3);
    };
    // N=1024 GEMMs stay on the 128^2 kernel (256^2 tiling would leave half the CUs idle)
    auto G = [&](const bf16_t* Ain, int wi, const float* bias, bf16_t* Cout, int Nn, int K,
                 int relu) {
      int nbx = Nn / 128;
      int shift = __builtin_ctz(nbx);
      gemm_bt_kernel<0><<<nbx * (NN / 128), 256, 0, stream>>>(
          Ain, WT + soff[wi], bias, nullptr, (void*)Cout, Nn, K, relu, shift);
    };

    agg0_kernel<<<NN / 2, 64, 0, stream>>>(B0, B1, rs, csr);
    G2(B1, 0, b1[0], B0, TT, 1);
    G2(B0, 1, b2[0], B1, HH, 1);
    AGG(B1, B0, HH, nullptr, 0);
    G2(B0, 2, b1[1], B1, HH, 1);
    G2(B1, 3, b2[1], B0, HH, 1);
    AGG(B0, B1, HH, nullptr, 0);
    G2(B1, 4, b1[2], B0, HH, 1);
    G2(B0, 5, b2[2], B1, HH, 1);
    // Layer 3 reordered: Y = x3 @ w1_3 (no bias); agg 1024-d fused b1_3+relu; then w2_3.
    G(B1, 6, nullptr, B0, OO, HH, 0);
    AGG(B0, B1, OO, b1[3], 1);
    G(B1, 7, b2[3], B0, OO, OO, 0);
    // Heads: wm|wv adjacent -> one N=256 GEMM, f32 split epilogue, direct bm/bv
    gemm_bt_kernel<1><<<2 * (NN / 128), 256, 0, stream>>>(
        B0, WT + soff[8], bm, bv, (void*)out, 256, OO, 0, 1);
  } else {
    // ---- fallback: interleaved scheme (shared 8.4MB WT) ----
    hipMemsetAsync(deg, 0, 2 * 8192 * sizeof(int), stream);
    count_deg_kernel<<<EE / 256, 256, 0, stream>>>(dst, deg);
    scan_kernel<<<1, 1024, 0, stream>>>(deg, rs);
    fill_csr_kernel<<<EE / 256, 256, 0, stream>>>(src, dst, rs, cur, csr);

    auto T = [&](const float* w, int K, int Nn, bf16_t* dstw, int packed) {
      transpose_cast_kernel<<<dim3(Nn / 64, K / 64), 256, 0, stream>>>(w, dstw, K, Nn, packed);
    };
    auto G2 = [&](const bf16_t* Ain, const float* bias, bf16_t* Cout, int K, int relu) {
      gemm256_kernel<<<8 * (NN / 256), 512, 0, stream>>>(Ain, WT, bias, Cout, HH, K, relu, 3);
    };
    auto G = [&](const bf16_t* Ain, const float* bias, bf16_t* Cout, int Nn, int K, int relu) {
      int nbx = Nn / 128;
      int shift = __builtin_ctz(nbx);
      gemm_bt_kernel<0><<<nbx * (NN / 128), 256, 0, stream>>>(
          Ain, WT, bias, nullptr, (void*)Cout, Nn, K, relu, shift);
    };

    cast_kernel<<<(NN * TT / 8) / 256, 256, 0, stream>>>(x0, B0);
    agg0_kernel<<<NN / 2, 64, 0, stream>>>(B0, B1, rs, csr);
    T(w1[0], TT, HH, WT, 1); G2(B1, b1[0], B0, TT, 1);
    T(w2[0], HH, HH, WT, 1); G2(B0, b2[0], B1, HH, 1);
    AGG(B1, B0, HH, nullptr, 0);
    T(w1[1], HH, HH, WT, 1); G2(B0, b1[1], B1, HH, 1);
    T(w2[1], HH, HH, WT, 1); G2(B1, b2[1], B0, HH, 1);
    AGG(B0, B1, HH, nullptr, 0);
    T(w1[2], HH, HH, WT, 1); G2(B1, b1[2], B0, HH, 1);
    T(w2[2], HH, HH, WT, 1); G2(B0, b2[2], B1, HH, 1);
    T(w1[3], HH, OO, WT, 0); G(B1, nullptr, B0, OO, HH, 0);
    AGG(B0, B1, OO, b1[3], 1);
    T(w2[3], OO, OO, WT, 0); G(B1, b2[3], B0, OO, OO, 0);
    T(wm, OO, LL, WT, 0);
    T(wv, OO, LL, WT + (size_t)LL * OO, 0);
    gemm_bt_kernel<1><<<2 * (NN / 128), 256, 0, stream>>>(
        B0, WT, bm, bv, (void*)out, 256, OO, 0, 1);
  }

  reparam_kernel<<<(NN * LL / 4) / 256, 256, 0, stream>>>(
      out + (size_t)NN * LL, out + (size_t)2 * NN * LL, eps, out);
}

// Round 7
// 826.256 us; speedup vs baseline: 1.0024x; 1.0024x over previous
//
#include <hip/hip_runtime.h>

#define NN 8192
#define EE 262144
#define TT 256
#define HH 2048
#define OO 1024
#define LL 128
#define NW 10

typedef __bf16 bf16_t;
typedef __bf16 bf16x8_t __attribute__((ext_vector_type(8)));
typedef float f32x4_t __attribute__((ext_vector_type(4)));

__device__ __forceinline__ void async16(void* lds, const void* g) {
  __builtin_amdgcn_global_load_lds(
      (const __attribute__((address_space(1))) void*)g,
      (__attribute__((address_space(3))) void*)lds, 16, 0, 0);
}

// Activations: 256-col tiled layout. elem(row,col) at (col>>8)*NN*256 + row*256 + (col&255).
// Empirically validated on this box (r8): workgroup -> XCD assignment is blockIdx % 8.

// ---------------- CSR build (dst-major) ----------------
__global__ __launch_bounds__(256) void count_deg_kernel(const int* __restrict__ dst,
                                                        int* __restrict__ deg) {
  int e = blockIdx.x * 256 + threadIdx.x;
  if (e < EE) atomicAdd(&deg[dst[e]], 1);
}

__global__ __launch_bounds__(1024) void scan_kernel(const int* __restrict__ deg,
                                                    int* __restrict__ rs) {
  __shared__ int s[1024];
  int t = threadIdx.x;
  int pre[8];
  int sum = 0;
#pragma unroll
  for (int j = 0; j < 8; ++j) { pre[j] = sum; sum += deg[t * 8 + j]; }
  s[t] = sum;
  __syncthreads();
  for (int off = 1; off < 1024; off <<= 1) {
    int add = (t >= off) ? s[t - off] : 0;
    __syncthreads();
    s[t] += add;
    __syncthreads();
  }
  int base = (t == 0) ? 0 : s[t - 1];
#pragma unroll
  for (int j = 0; j < 8; ++j) rs[t * 8 + j] = base + pre[j];
  if (t == 1023) rs[8192] = s[1023];
}

__global__ __launch_bounds__(256) void fill_csr_kernel(const int* __restrict__ src,
                                                       const int* __restrict__ dst,
                                                       const int* __restrict__ rs,
                                                       int* __restrict__ cur,
                                                       int* __restrict__ csr) {
  int e = blockIdx.x * 256 + threadIdx.x;
  if (e >= EE) return;
  int d = dst[e];
  int p = atomicAdd(&cur[d], 1);
  csr[rs[d] + p] = src[e];
}

// ---------------- merged prep: all 9 weight transposes + x0 cast ----------------
struct WTab {
  const float* src[NW];
  int K[NW];
  int N[NW];
  long long dstOff[NW];
  int tileStart[NW + 1];
  const float* x0;
  bf16_t* castDst;
  int castStart;
};

__global__ __launch_bounds__(256) void prep_all_kernel(WTab tab, bf16_t* __restrict__ WT) {
  int b = blockIdx.x;
  int t = threadIdx.x;
  if (b >= tab.castStart) {
    int i = (b - tab.castStart) * 256 + t;
    f32x4_t a = ((const f32x4_t*)tab.x0)[i * 2];
    f32x4_t bb = ((const f32x4_t*)tab.x0)[i * 2 + 1];
    bf16x8_t o;
#pragma unroll
    for (int j = 0; j < 4; ++j) { o[j] = (bf16_t)a[j]; o[4 + j] = (bf16_t)bb[j]; }
    ((bf16x8_t*)tab.castDst)[i] = o;
    return;
  }
  int wi = 0;
#pragma unroll
  for (int k = 1; k < NW; ++k)
    if (b >= tab.tileStart[k]) wi = k;
  int tt = b - tab.tileStart[wi];
  int K = tab.K[wi], N = tab.N[wi];
  int ntn = N >> 6;
  int n0 = (tt % ntn) * 64, k0 = (tt / ntn) * 64;
  const float* in = tab.src[wi];
  bf16_t* out = WT + tab.dstOff[wi];

  __shared__ float tile[64][65];
  for (int c = t; c < 1024; c += 256) {
    int r = c >> 4, col = (c & 15) * 4;
    f32x4_t v = *(const f32x4_t*)&in[(size_t)(k0 + r) * N + n0 + col];
#pragma unroll
    for (int j = 0; j < 4; ++j) tile[r][col + j] = v[j];
  }
  __syncthreads();
  for (int c = t; c < 512; c += 256) {
    int r = c >> 3, col = (c & 7) * 8;
    bf16x8_t v;
#pragma unroll
    for (int j = 0; j < 8; ++j) v[j] = (bf16_t)tile[col + j][r];
    *(bf16x8_t*)&out[(size_t)(n0 + r) * K + k0 + col] = v;
  }
}

// ---------------- standalone transpose+cast (fallback path) ----------------
__global__ __launch_bounds__(256) void transpose_cast_kernel(const float* __restrict__ in,
                                                             bf16_t* __restrict__ out,
                                                             int K, int N) {
  __shared__ float tile[64][65];
  int n0 = blockIdx.x * 64, k0 = blockIdx.y * 64;
  int t = threadIdx.x;
  for (int c = t; c < 1024; c += 256) {
    int r = c >> 4, col = (c & 15) * 4;
    f32x4_t v = *(const f32x4_t*)&in[(size_t)(k0 + r) * N + n0 + col];
#pragma unroll
    for (int j = 0; j < 4; ++j) tile[r][col + j] = v[j];
  }
  __syncthreads();
  for (int c = t; c < 512; c += 256) {
    int r = c >> 3, col = (c & 7) * 8;
    bf16x8_t v;
#pragma unroll
    for (int j = 0; j < 8; ++j) v[j] = (bf16_t)tile[col + j][r];
    *(bf16x8_t*)&out[(size_t)(n0 + r) * K + k0 + col] = v;
  }
}

__global__ __launch_bounds__(256) void cast_kernel(const float* __restrict__ in,
                                                   bf16_t* __restrict__ out) {
  int i = blockIdx.x * 256 + threadIdx.x;
  f32x4_t a = ((const f32x4_t*)in)[i * 2];
  f32x4_t b = ((const f32x4_t*)in)[i * 2 + 1];
  bf16x8_t o;
#pragma unroll
  for (int j = 0; j < 4; ++j) { o[j] = (bf16_t)a[j]; o[4 + j] = (bf16_t)b[j]; }
  ((bf16x8_t*)out)[i] = o;
}

// ------- layer-0 aggregation, d=256 -------
__global__ __launch_bounds__(64) void agg0_kernel(const bf16_t* __restrict__ x,
                                                  bf16_t* __restrict__ out,
                                                  const int* __restrict__ rs,
                                                  const int* __restrict__ csr) {
  int t = threadIdx.x;
  int node = blockIdx.x * 2 + (t >> 5);
  int c = t & 31;
  const bf16x8_t* xv = (const bf16x8_t*)x;
  bf16x8_t self = xv[(size_t)node * 32 + c];
  float acc[8];
#pragma unroll
  for (int j = 0; j < 8; ++j) acc[j] = (float)self[j];
  int e0 = rs[node], e1 = rs[node + 1];
  int e = e0;
  for (; e + 4 <= e1; e += 4) {
    int s0 = csr[e], s1 = csr[e + 1], s2 = csr[e + 2], s3 = csr[e + 3];
    bf16x8_t v0 = xv[(size_t)s0 * 32 + c];
    bf16x8_t v1 = xv[(size_t)s1 * 32 + c];
    bf16x8_t v2 = xv[(size_t)s2 * 32 + c];
    bf16x8_t v3 = xv[(size_t)s3 * 32 + c];
#pragma unroll
    for (int j = 0; j < 8; ++j)
      acc[j] += (float)v0[j] + (float)v1[j] + (float)v2[j] + (float)v3[j];
  }
  for (; e < e1; ++e) {
    bf16x8_t v = xv[(size_t)csr[e] * 32 + c];
#pragma unroll
    for (int j = 0; j < 8; ++j) acc[j] += (float)v[j];
  }
  bf16x8_t o;
#pragma unroll
  for (int j = 0; j < 8; ++j) o[j] = (bf16_t)acc[j];
  __builtin_nontemporal_store(o, (bf16x8_t*)out + (size_t)node * 32 + c);
}

// ------- aggregation over tiled activations, XCD-pinned tiles (validated r8) -------
// L2-residency fix (r7): output written with NONTEMPORAL stores. Per XCD, the gather
// working set is the 4MB input tile; streaming output write-allocates were evicting
// input lines between their ~33 reuses (input 4MB + output 4MB > 4MB L2). nt store
// keeps the input resident; output streams to L3/HBM (coherent for the next kernel).
// Edge loop unrolled 8-wide (8 independent 16B loads in flight).
__global__ __launch_bounds__(256) void agg_tiled_kernel(const bf16_t* __restrict__ x,
                                                        bf16_t* __restrict__ out,
                                                        const int* __restrict__ rs,
                                                        const int* __restrict__ csr,
                                                        const float* __restrict__ bias,
                                                        int relu, int tmask, int tshift) {
  int t = threadIdx.x;
  int tile = blockIdx.x & tmask;
  int ng = blockIdx.x >> tshift;
  int node = ng * 8 + (t >> 5);
  int c = t & 31;
  size_t tb = (size_t)tile * (NN * 32);
  const bf16x8_t* xv = (const bf16x8_t*)x + tb;
  bf16x8_t self = xv[node * 32 + c];
  float acc[8];
#pragma unroll
  for (int j = 0; j < 8; ++j) acc[j] = (float)self[j];
  int e0 = rs[node], e1 = rs[node + 1];
  int e = e0;
  for (; e + 8 <= e1; e += 8) {
    int s0 = csr[e], s1 = csr[e + 1], s2 = csr[e + 2], s3 = csr[e + 3];
    int s4 = csr[e + 4], s5 = csr[e + 5], s6 = csr[e + 6], s7 = csr[e + 7];
    bf16x8_t v0 = xv[s0 * 32 + c];
    bf16x8_t v1 = xv[s1 * 32 + c];
    bf16x8_t v2 = xv[s2 * 32 + c];
    bf16x8_t v3 = xv[s3 * 32 + c];
    bf16x8_t v4 = xv[s4 * 32 + c];
    bf16x8_t v5 = xv[s5 * 32 + c];
    bf16x8_t v6 = xv[s6 * 32 + c];
    bf16x8_t v7 = xv[s7 * 32 + c];
#pragma unroll
    for (int j = 0; j < 8; ++j)
      acc[j] += (((float)v0[j] + (float)v1[j]) + ((float)v2[j] + (float)v3[j])) +
                (((float)v4[j] + (float)v5[j]) + ((float)v6[j] + (float)v7[j]));
  }
  for (; e + 4 <= e1; e += 4) {
    int s0 = csr[e], s1 = csr[e + 1], s2 = csr[e + 2], s3 = csr[e + 3];
    bf16x8_t v0 = xv[s0 * 32 + c];
    bf16x8_t v1 = xv[s1 * 32 + c];
    bf16x8_t v2 = xv[s2 * 32 + c];
    bf16x8_t v3 = xv[s3 * 32 + c];
#pragma unroll
    for (int j = 0; j < 8; ++j)
      acc[j] += (float)v0[j] + (float)v1[j] + (float)v2[j] + (float)v3[j];
  }
  for (; e < e1; ++e) {
    bf16x8_t v = xv[csr[e] * 32 + c];
#pragma unroll
    for (int j = 0; j < 8; ++j) acc[j] += (float)v[j];
  }
  if (bias) {
    const float* bp = bias + tile * 256 + c * 8;
    f32x4_t b0 = *(const f32x4_t*)bp;
    f32x4_t b1 = *(const f32x4_t*)(bp + 4);
#pragma unroll
    for (int j = 0; j < 4; ++j) { acc[j] += b0[j]; acc[4 + j] += b1[j]; }
  }
  if (relu) {
#pragma unroll
    for (int j = 0; j < 8; ++j) acc[j] = fmaxf(acc[j], 0.f);
  }
  bf16x8_t o;
#pragma unroll
  for (int j = 0; j < 8; ++j) o[j] = (bf16_t)acc[j];
  __builtin_nontemporal_store(o, (bf16x8_t*)out + tb + node * 32 + c);
}

// ------- OLD GEMM (128x128 tile): kept for N=1024 GEMMs and the heads GEMM -------
template <int CMODE>
__global__ __launch_bounds__(256, 2) void gemm_bt_kernel(
    const bf16_t* __restrict__ A, const bf16_t* __restrict__ Bt,
    const float* __restrict__ bias, const float* __restrict__ biasB,
    void* __restrict__ Cv, int N, int K, int relu, int nbxShift) {
  __shared__ __align__(16) bf16_t lA[128 * 32];
  __shared__ __align__(16) bf16_t lB[128 * 32];
  const int tid = threadIdx.x;
  const int lane = tid & 63;
  const int wave = tid >> 6;
  const int wm64 = (wave & 1) * 64;
  const int wn64 = (wave >> 1) * 64;
  const int row16 = lane & 15;
  const int quad = lane >> 4;

  const int bid = blockIdx.x;
  const int xcd = bid & 7;
  const int rank = bid >> 3;
  const int bn = rank & ((1 << nbxShift) - 1);
  const int mPer = gridDim.x >> (3 + nbxShift);
  const int bm = xcd * mPer + (rank >> nbxShift);
  const size_t m0 = (size_t)bm * 128;
  const size_t n0 = (size_t)bn * 128;

  f32x4_t acc[4][4];
#pragma unroll
  for (int i = 0; i < 4; ++i)
#pragma unroll
    for (int j = 0; j < 4; ++j)
#pragma unroll
      for (int r = 0; r < 4; ++r) acc[i][j][r] = 0.f;

  const bf16_t* Bbase = Bt + n0 * K;
  const int r0 = tid >> 2;
  const int r1 = (tid + 256) >> 2;
  const int kc = (tid & 3) * 8;

  for (int kt = 0; kt < K; kt += 32) {
    const bf16_t* Ab = A + ((size_t)(kt >> 8)) * (NN * 256) + (kt & 255) + kc;
    async16(&lA[tid * 8], Ab + (m0 + r0) * 256);
    async16(&lA[(tid + 256) * 8], Ab + (m0 + r1) * 256);
    async16(&lB[tid * 8], Bbase + (size_t)r0 * K + kt + kc);
    async16(&lB[(tid + 256) * 8], Bbase + (size_t)r1 * K + kt + kc);
    __syncthreads();
    bf16x8_t af[4], bfr[4];
#pragma unroll
    for (int i = 0; i < 4; ++i)
      af[i] = *(const bf16x8_t*)&lA[(wm64 + i * 16 + row16) * 32 + quad * 8];
#pragma unroll
    for (int i = 0; i < 4; ++i)
      bfr[i] = *(const bf16x8_t*)&lB[(wn64 + i * 16 + row16) * 32 + quad * 8];
#pragma unroll
    for (int i = 0; i < 4; ++i)
#pragma unroll
      for (int j = 0; j < 4; ++j)
        acc[i][j] = __builtin_amdgcn_mfma_f32_16x16x32_bf16(af[i], bfr[j], acc[i][j], 0, 0, 0);
    __syncthreads();
  }

  // C/D layout: col = lane&15, row = quad*4 + reg  [verified m89/m91]
#pragma unroll
  for (int i = 0; i < 4; ++i) {
    size_t row = m0 + wm64 + i * 16 + quad * 4;
#pragma unroll
    for (int j = 0; j < 4; ++j) {
      int col = (int)n0 + wn64 + j * 16 + row16;
      if (CMODE == 0) {
        float b = bias ? bias[col] : 0.f;
        size_t cb = ((size_t)(col >> 8)) * (NN * 256) + (col & 255);
#pragma unroll
        for (int r = 0; r < 4; ++r) {
          float o = acc[i][j][r] + b;
          if (relu) o = fmaxf(o, 0.f);
          ((bf16_t*)Cv)[cb + (row + r) * 256] = (bf16_t)o;
        }
      } else {
        int sel = col >> 7;
        int c2 = col & 127;
        float b = sel ? biasB[c2] : bias[c2];
        float* dstp = (float*)Cv + (size_t)(1 + sel) * NN * LL + c2;
#pragma unroll
        for (int r = 0; r < 4; ++r) {
          dstp[(row + r) * LL] = acc[i][j][r] + b;
        }
      }
    }
  }
}

// ------- NEW GEMM: 256x256 tile, BK=64, 8-wave -- r1 structure + persistent B regs -------
// (r5, best-known 71.0us / 965 TF -- FROZEN this round)
// Phase reads {12,4,8,0}, 8 barriers/K-tile, tile-end vmcnt(4), staging 2 asyncs/phase.
// WAR/RAW safety as derived in r5 comments. LDS read swizzle elem^=(row&7)<<3; inverse
// pre-applied to the GLOBAL source so the global_load_lds dest stays linear (rule #21).
__global__ __launch_bounds__(512, 2) void gemm256_kernel(
    const bf16_t* __restrict__ A, const bf16_t* __restrict__ Bt,
    const float* __restrict__ bias, bf16_t* __restrict__ C,
    int N, int K, int relu, int nbxShift) {
  __shared__ __align__(16) bf16_t lA[2][256 * 64];
  __shared__ __align__(16) bf16_t lB[2][256 * 64];

  const int t = threadIdx.x;
  const int lane = t & 63;
  const int wave = t >> 6;
  const int wm = wave >> 2;  // 0..1
  const int wn = wave & 3;   // 0..3
  const int row16 = lane & 15;
  const int quad = lane >> 4;
  const int sx = (row16 & 7) << 3;  // read-side swizzle XOR (elements)

  // staging constants: thread t covers rows r0 and r0+64 of a 128-row half, 8 elems each
  const int r0 = t >> 3;
  const int cs = ((t & 7) * 8) ^ ((r0 & 7) << 3);  // pre-swizzled source column (elements)

  const int bid = blockIdx.x;
  const int xcd = bid & 7;
  const int rank = bid >> 3;
  const int bn = rank & ((1 << nbxShift) - 1);
  const int mPer = gridDim.x >> (3 + nbxShift);
  const int bm = xcd * mPer + (rank >> nbxShift);
  const size_t m0 = (size_t)bm * 256;
  const size_t n0 = (size_t)bn * 256;
  const int NT = K >> 6;

  f32x4_t acc[4][4][2];
#pragma unroll
  for (int Q = 0; Q < 4; ++Q)
#pragma unroll
    for (int i = 0; i < 4; ++i)
#pragma unroll
      for (int j = 0; j < 2; ++j)
#pragma unroll
        for (int r = 0; r < 4; ++r) acc[Q][i][j][r] = 0.f;

  bf16x8_t af[4][2], bfA[2][2], bfB[2][2];

#define LOAD_A(mh)                                                                 \
  _Pragma("unroll") for (int i = 0; i < 4; ++i)                                    \
  _Pragma("unroll") for (int ks = 0; ks < 2; ++ks) {                               \
    int row_ = (mh)*128 + wm * 64 + i * 16 + row16;                                \
    af[i][ks] = *(const bf16x8_t*)&lA[c][row_ * 64 + ((ks * 32 + quad * 8) ^ sx)]; \
  }

#define LOAD_B(dstv, nh)                                                             \
  _Pragma("unroll") for (int j = 0; j < 2; ++j)                                      \
  _Pragma("unroll") for (int ks = 0; ks < 2; ++ks) {                                 \
    int row_ = (nh)*128 + wn * 32 + j * 16 + row16;                                  \
    dstv[j][ks] = *(const bf16x8_t*)&lB[c][row_ * 64 + ((ks * 32 + quad * 8) ^ sx)]; \
  }

#define STAGE_A256(U, mh)                                                            \
  {                                                                                  \
    int u_ = (U);                                                                    \
    int us_ = u_ < NT ? u_ : NT - 1;                                                 \
    int kt_ = us_ << 6;                                                              \
    const bf16_t* g_ = A + (size_t)(kt_ >> 8) * (NN * 256) + (m0 + (mh)*128) * 256 + \
                       (kt_ & 255) + cs;                                             \
    bf16_t* l_ = &lA[u_ & 1][(mh)*8192];                                             \
    async16(l_ + (size_t)t * 8, g_ + (size_t)r0 * 256);                              \
    async16(l_ + (size_t)(t + 512) * 8, g_ + (size_t)(r0 + 64) * 256);               \
  }

#define STAGE_B256(U, nh)                                                  \
  {                                                                        \
    int u_ = (U);                                                          \
    int us_ = u_ < NT ? u_ : NT - 1;                                       \
    int kt_ = us_ << 6;                                                    \
    const bf16_t* g_ = Bt + (n0 + (nh)*128) * (size_t)K + kt_ + cs;        \
    bf16_t* l_ = &lB[u_ & 1][(nh)*8192];                                   \
    async16(l_ + (size_t)t * 8, g_ + (size_t)r0 * K);                      \
    async16(l_ + (size_t)(t + 512) * 8, g_ + (size_t)(r0 + 64) * K);       \
  }

#define MFMA_Q(Q, BFX)                                                               \
  __builtin_amdgcn_s_setprio(1);                                                     \
  _Pragma("unroll") for (int i = 0; i < 4; ++i)                                      \
  _Pragma("unroll") for (int j = 0; j < 2; ++j)                                      \
  _Pragma("unroll") for (int ks = 0; ks < 2; ++ks)                                   \
      acc[Q][i][j] = __builtin_amdgcn_mfma_f32_16x16x32_bf16(                        \
          af[i][ks], BFX[j][ks], acc[Q][i][j], 0, 0, 0);                             \
  __builtin_amdgcn_s_setprio(0);

#define BAR asm volatile("s_barrier" ::: "memory")

  // Prologue: tile0 (4 halves) + A0/B0 of tile1. Fence pins issue order so
  // vmcnt(4) drains exactly tile0's 8 loads, leaving A0/B0(1) in flight.
  STAGE_A256(0, 0); STAGE_B256(0, 0); STAGE_A256(0, 1); STAGE_B256(0, 1);
  asm volatile("" ::: "memory");
  STAGE_A256(1, 0); STAGE_B256(1, 0);
  asm volatile("s_waitcnt vmcnt(4)" ::: "memory");
  BAR;

  for (int T = 0; T < NT; ++T) {
    const int c = T & 1;
    // q0: (0,0) -- 12 reads; pre-bar counted lgkm drains the burst partially
    LOAD_A(0);
    LOAD_B(bfA, 0);
    STAGE_A256(T + 1, 1);
    asm volatile("s_waitcnt lgkmcnt(8)" ::: "memory");
    BAR;
    MFMA_Q(0, bfA);
    BAR;
    // q1: (0,1) -- 4 reads
    LOAD_B(bfB, 1);
    STAGE_B256(T + 1, 1);
    BAR;
    MFMA_Q(1, bfB);
    BAR;
    // q2: (1,0) -- 8 reads (B persistent in bfA, no re-read)
    LOAD_A(1);
    STAGE_A256(T + 2, 0);
    BAR;
    MFMA_Q(2, bfA);
    BAR;
    // q3: (1,1) -- 0 reads (B persistent in bfB)
    STAGE_B256(T + 2, 0);
    BAR;
    MFMA_Q(3, bfB);
    asm volatile("s_waitcnt vmcnt(4)" ::: "memory");
    BAR;
  }
  asm volatile("s_waitcnt vmcnt(0)" ::: "memory");

  // Epilogue: C/D layout col = lane&15, row = quad*4 + reg [verified m89/m91]
#pragma unroll
  for (int Q = 0; Q < 4; ++Q) {
    const int mh = Q >> 1, nh = Q & 1;
#pragma unroll
    for (int i = 0; i < 4; ++i) {
      size_t row = m0 + mh * 128 + wm * 64 + i * 16 + quad * 4;
#pragma unroll
      for (int j = 0; j < 2; ++j) {
        int col = (int)n0 + nh * 128 + wn * 32 + j * 16 + row16;
        float b = bias ? bias[col] : 0.f;
        size_t cb = ((size_t)(col >> 8)) * (NN * 256) + (col & 255);
#pragma unroll
        for (int r = 0; r < 4; ++r) {
          float o = acc[Q][i][j][r] + b;
          if (relu) o = fmaxf(o, 0.f);
          C[cb + (row + r) * 256] = (bf16_t)o;
        }
      }
    }
  }
#undef LOAD_A
#undef LOAD_B
#undef STAGE_A256
#undef STAGE_B256
#undef MFMA_Q
#undef BAR
}

// ---------------- z = mean + var*eps (f32) ----------------
__global__ __launch_bounds__(256) void reparam_kernel(const float* __restrict__ mean,
                                                      const float* __restrict__ var,
                                                      const float* __restrict__ eps,
                                                      float* __restrict__ z) {
  int i = blockIdx.x * 256 + threadIdx.x;
  f32x4_t m = ((const f32x4_t*)mean)[i];
  f32x4_t v = ((const f32x4_t*)var)[i];
  f32x4_t e = ((const f32x4_t*)eps)[i];
  f32x4_t o;
#pragma unroll
  for (int j = 0; j < 4; ++j) o[j] = m[j] + v[j] * e[j];
  __builtin_nontemporal_store(o, (f32x4_t*)z + i);
}

extern "C" void kernel_launch(void* const* d_in, const int* in_sizes, int n_in,
                              void* d_out, int out_size, void* d_ws, size_t ws_size,
                              hipStream_t stream) {
  (void)in_sizes; (void)n_in; (void)out_size;
  const float* x0 = (const float*)d_in[0];
  const int* ei = (const int*)d_in[1];
  const int* src = ei;
  const int* dst = ei + EE;
  const float* w1[4] = {(const float*)d_in[2], (const float*)d_in[6],
                        (const float*)d_in[10], (const float*)d_in[14]};
  const float* b1[4] = {(const float*)d_in[3], (const float*)d_in[7],
                        (const float*)d_in[11], (const float*)d_in[15]};
  const float* w2[4] = {(const float*)d_in[4], (const float*)d_in[8],
                        (const float*)d_in[12], (const float*)d_in[16]};
  const float* b2[4] = {(const float*)d_in[5], (const float*)d_in[9],
                        (const float*)d_in[13], (const float*)d_in[17]};
  const float* wm = (const float*)d_in[18];
  const float* bm = (const float*)d_in[19];
  const float* wv = (const float*)d_in[20];
  const float* bv = (const float*)d_in[21];
  const float* eps = (const float*)d_in[22];
  float* out = (float*)d_out;

  char* ws = (char*)d_ws;
  bf16_t* B0 = (bf16_t*)(ws);
  bf16_t* B1 = (bf16_t*)(ws + 33554432);
  bf16_t* WT = (bf16_t*)(ws + 67108864);

  // Per-weight WT slot offsets (bf16 elems), order: w1_0,w2_0,w1_1,w2_1,w1_2,w2_2,w1_3,w2_3,wm,wv
  const long long soff[NW] = {0LL, 524288LL, 4718592LL, 8912896LL, 13107200LL,
                              17301504LL, 21495808LL, 23592960LL, 24641536LL, 24772608LL};
  const size_t wtBytesFull = 24903680ULL * 2ULL;          // 49.8 MB
  const size_t needFull = 67108864ULL + wtBytesFull + 2097152ULL;
  bool full = ws_size >= needFull;

  size_t csrBase = full ? (67108864ULL + wtBytesFull) : 75497472ULL;
  int* deg = (int*)(ws + csrBase);
  int* cur = deg + 8192;
  int* rs = deg + 16384;
  int* csr = deg + 16384 + 8200;

  auto AGG = [&](const bf16_t* in, bf16_t* outp, int d, const float* bias, int relu) {
    int ntiles = d >> 8;
    int tshift = (ntiles == 8) ? 3 : 2;
    agg_tiled_kernel<<<(NN / 8) * ntiles, 256, 0, stream>>>(in, outp, rs, csr, bias, relu,
                                                            ntiles - 1, tshift);
  };

  if (full) {
    // ---- merged prep: all transposes + x0 cast in one dispatch ----
    WTab tab;
    const float* srcs[NW] = {w1[0], w2[0], w1[1], w2[1], w1[2], w2[2], w1[3], w2[3], wm, wv};
    const int Ks[NW] = {TT, HH, HH, HH, HH, HH, HH, OO, OO, OO};
    const int Ns[NW] = {HH, HH, HH, HH, HH, HH, OO, OO, LL, LL};
    int cum = 0;
    for (int i = 0; i < NW; ++i) {
      tab.src[i] = srcs[i];
      tab.K[i] = Ks[i];
      tab.N[i] = Ns[i];
      tab.dstOff[i] = soff[i];
      tab.tileStart[i] = cum;
      cum += (Ns[i] >> 6) * (Ks[i] >> 6);
    }
    tab.tileStart[NW] = cum;
    tab.castStart = cum;
    tab.x0 = x0;
    tab.castDst = B0;
    int totalBlocks = cum + (NN * TT / 8) / 256;
    prep_all_kernel<<<totalBlocks, 256, 0, stream>>>(tab, WT);

    hipMemsetAsync(deg, 0, 2 * 8192 * sizeof(int), stream);
    count_deg_kernel<<<EE / 256, 256, 0, stream>>>(dst, deg);
    scan_kernel<<<1, 1024, 0, stream>>>(deg, rs);
    fill_csr_kernel<<<EE / 256, 256, 0, stream>>>(src, dst, rs, cur, csr);

    // N=2048 GEMMs -> 256^2 kernel (grid 256 = 1 block/CU, nbxShift=3)
    auto G2 = [&](const bf16_t* Ain, int wi, const float* bias, bf16_t* Cout, int K, int relu) {
      gemm256_kernel<<<8 * (NN / 256), 512, 0, stream>>>(Ain, WT + soff[wi], bias, Cout,
                                                         HH, K, relu, 3);
    };
    // N=1024 GEMMs stay on the 128^2 kernel (256^2 tiling would leave half the CUs idle)
    auto G = [&](const bf16_t* Ain, int wi, const float* bias, bf16_t* Cout, int Nn, int K,
                 int relu) {
      int nbx = Nn / 128;
      int shift = __builtin_ctz(nbx);
      gemm_bt_kernel<0><<<nbx * (NN / 128), 256, 0, stream>>>(
          Ain, WT + soff[wi], bias, nullptr, (void*)Cout, Nn, K, relu, shift);
    };

    agg0_kernel<<<NN / 2, 64, 0, stream>>>(B0, B1, rs, csr);
    G2(B1, 0, b1[0], B0, TT, 1);
    G2(B0, 1, b2[0], B1, HH, 1);
    AGG(B1, B0, HH, nullptr, 0);
    G2(B0, 2, b1[1], B1, HH, 1);
    G2(B1, 3, b2[1], B0, HH, 1);
    AGG(B0, B1, HH, nullptr, 0);
    G2(B1, 4, b1[2], B0, HH, 1);
    G2(B0, 5, b2[2], B1, HH, 1);
    // Layer 3 reordered: Y = x3 @ w1_3 (no bias); agg 1024-d fused b1_3+relu; then w2_3.
    G(B1, 6, nullptr, B0, OO, HH, 0);
    AGG(B0, B1, OO, b1[3], 1);
    G(B1, 7, b2[3], B0, OO, OO, 0);
    // Heads: wm|wv adjacent -> one N=256 GEMM, f32 split epilogue, direct bm/bv
    gemm_bt_kernel<1><<<2 * (NN / 128), 256, 0, stream>>>(
        B0, WT + soff[8], bm, bv, (void*)out, 256, OO, 0, 1);
  } else {
    // ---- fallback: interleaved scheme (shared 8.4MB WT) ----
    hipMemsetAsync(deg, 0, 2 * 8192 * sizeof(int), stream);
    count_deg_kernel<<<EE / 256, 256, 0, stream>>>(dst, deg);
    scan_kernel<<<1, 1024, 0, stream>>>(deg, rs);
    fill_csr_kernel<<<EE / 256, 256, 0, stream>>>(src, dst, rs, cur, csr);

    auto T = [&](const float* w, int K, int Nn, bf16_t* dstw) {
      transpose_cast_kernel<<<dim3(Nn / 64, K / 64), 256, 0, stream>>>(w, dstw, K, Nn);
    };
    auto G2 = [&](const bf16_t* Ain, const float* bias, bf16_t* Cout, int K, int relu) {
      gemm256_kernel<<<8 * (NN / 256), 512, 0, stream>>>(Ain, WT, bias, Cout, HH, K, relu, 3);
    };
    auto G = [&](const bf16_t* Ain, const float* bias, bf16_t* Cout, int Nn, int K, int relu) {
      int nbx = Nn / 128;
      int shift = __builtin_ctz(nbx);
      gemm_bt_kernel<0><<<nbx * (NN / 128), 256, 0, stream>>>(
          Ain, WT, bias, nullptr, (void*)Cout, Nn, K, relu, shift);
    };

    cast_kernel<<<(NN * TT / 8) / 256, 256, 0, stream>>>(x0, B0);
    agg0_kernel<<<NN / 2, 64, 0, stream>>>(B0, B1, rs, csr);
    T(w1[0], TT, HH, WT); G2(B1, b1[0], B0, TT, 1);
    T(w2[0], HH, HH, WT); G2(B0, b2[0], B1, HH, 1);
    AGG(B1, B0, HH, nullptr, 0);
    T(w1[1], HH, HH, WT); G2(B0, b1[1], B1, HH, 1);
    T(w2[1], HH, HH, WT); G2(B1, b2[1], B0, HH, 1);
    AGG(B0, B1, HH, nullptr, 0);
    T(w1[2], HH, HH, WT); G2(B1, b1[2], B0, HH, 1);
    T(w2[2], HH, HH, WT); G2(B0, b2[2], B1, HH, 1);
    T(w1[3], HH, OO, WT); G(B1, nullptr, B0, OO, HH, 0);
    AGG(B0, B1, OO, b1[3], 1);
    T(w2[3], OO, OO, WT); G(B1, b2[3], B0, OO, OO, 0);
    T(wm, OO, LL, WT);
    T(wv, OO, LL, WT + (size_t)LL * OO);
    gemm_bt_kernel<1><<<2 * (NN / 128), 256, 0, stream>>>(
        B0, WT, bm, bv, (void*)out, 256, OO, 0, 1);
  }

  reparam_kernel<<<(NN * LL / 4) / 256, 256, 0, stream>>>(
      out + (size_t)NN * LL, out + (size_t)2 * NN * LL, eps, out);
}

// Round 8
// 805.762 us; speedup vs baseline: 1.0279x; 1.0254x over previous
//
#include <hip/hip_runtime.h>

#define NN 8192
#define EE 262144
#define TT 256
#define HH 2048
#define OO 1024
#define LL 128
#define NW 10

typedef __bf16 bf16_t;
typedef __bf16 bf16x8_t __attribute__((ext_vector_type(8)));
typedef float f32x4_t __attribute__((ext_vector_type(4)));

__device__ __forceinline__ void async16(void* lds, const void* g) {
  __builtin_amdgcn_global_load_lds(
      (const __attribute__((address_space(1))) void*)g,
      (__attribute__((address_space(3))) void*)lds, 16, 0, 0);
}

// Activations: 256-col tiled layout. elem(row,col) at (col>>8)*NN*256 + row*256 + (col&255).
// Empirically validated on this box (r8): workgroup -> XCD assignment is blockIdx % 8.

// ---------------- CSR build (dst-major) ----------------
__global__ __launch_bounds__(256) void count_deg_kernel(const int* __restrict__ dst,
                                                        int* __restrict__ deg) {
  int e = blockIdx.x * 256 + threadIdx.x;
  if (e < EE) atomicAdd(&deg[dst[e]], 1);
}

__global__ __launch_bounds__(1024) void scan_kernel(const int* __restrict__ deg,
                                                    int* __restrict__ rs) {
  __shared__ int s[1024];
  int t = threadIdx.x;
  int pre[8];
  int sum = 0;
#pragma unroll
  for (int j = 0; j < 8; ++j) { pre[j] = sum; sum += deg[t * 8 + j]; }
  s[t] = sum;
  __syncthreads();
  for (int off = 1; off < 1024; off <<= 1) {
    int add = (t >= off) ? s[t - off] : 0;
    __syncthreads();
    s[t] += add;
    __syncthreads();
  }
  int base = (t == 0) ? 0 : s[t - 1];
#pragma unroll
  for (int j = 0; j < 8; ++j) rs[t * 8 + j] = base + pre[j];
  if (t == 1023) rs[8192] = s[1023];
}

__global__ __launch_bounds__(256) void fill_csr_kernel(const int* __restrict__ src,
                                                       const int* __restrict__ dst,
                                                       const int* __restrict__ rs,
                                                       int* __restrict__ cur,
                                                       int* __restrict__ csr) {
  int e = blockIdx.x * 256 + threadIdx.x;
  if (e >= EE) return;
  int d = dst[e];
  int p = atomicAdd(&cur[d], 1);
  csr[rs[d] + p] = src[e];
}

// ---------------- merged prep: all 9 weight transposes + x0 cast ----------------
struct WTab {
  const float* src[NW];
  int K[NW];
  int N[NW];
  long long dstOff[NW];
  int tileStart[NW + 1];
  const float* x0;
  bf16_t* castDst;
  int castStart;
};

__global__ __launch_bounds__(256) void prep_all_kernel(WTab tab, bf16_t* __restrict__ WT) {
  int b = blockIdx.x;
  int t = threadIdx.x;
  if (b >= tab.castStart) {
    int i = (b - tab.castStart) * 256 + t;
    f32x4_t a = ((const f32x4_t*)tab.x0)[i * 2];
    f32x4_t bb = ((const f32x4_t*)tab.x0)[i * 2 + 1];
    bf16x8_t o;
#pragma unroll
    for (int j = 0; j < 4; ++j) { o[j] = (bf16_t)a[j]; o[4 + j] = (bf16_t)bb[j]; }
    ((bf16x8_t*)tab.castDst)[i] = o;
    return;
  }
  int wi = 0;
#pragma unroll
  for (int k = 1; k < NW; ++k)
    if (b >= tab.tileStart[k]) wi = k;
  int tt = b - tab.tileStart[wi];
  int K = tab.K[wi], N = tab.N[wi];
  int ntn = N >> 6;
  int n0 = (tt % ntn) * 64, k0 = (tt / ntn) * 64;
  const float* in = tab.src[wi];
  bf16_t* out = WT + tab.dstOff[wi];

  __shared__ float tile[64][65];
  for (int c = t; c < 1024; c += 256) {
    int r = c >> 4, col = (c & 15) * 4;
    f32x4_t v = *(const f32x4_t*)&in[(size_t)(k0 + r) * N + n0 + col];
#pragma unroll
    for (int j = 0; j < 4; ++j) tile[r][col + j] = v[j];
  }
  __syncthreads();
  for (int c = t; c < 512; c += 256) {
    int r = c >> 3, col = (c & 7) * 8;
    bf16x8_t v;
#pragma unroll
    for (int j = 0; j < 8; ++j) v[j] = (bf16_t)tile[col + j][r];
    *(bf16x8_t*)&out[(size_t)(n0 + r) * K + k0 + col] = v;
  }
}

// ---------------- standalone transpose+cast (fallback path) ----------------
__global__ __launch_bounds__(256) void transpose_cast_kernel(const float* __restrict__ in,
                                                             bf16_t* __restrict__ out,
                                                             int K, int N) {
  __shared__ float tile[64][65];
  int n0 = blockIdx.x * 64, k0 = blockIdx.y * 64;
  int t = threadIdx.x;
  for (int c = t; c < 1024; c += 256) {
    int r = c >> 4, col = (c & 15) * 4;
    f32x4_t v = *(const f32x4_t*)&in[(size_t)(k0 + r) * N + n0 + col];
#pragma unroll
    for (int j = 0; j < 4; ++j) tile[r][col + j] = v[j];
  }
  __syncthreads();
  for (int c = t; c < 512; c += 256) {
    int r = c >> 3, col = (c & 7) * 8;
    bf16x8_t v;
#pragma unroll
    for (int j = 0; j < 8; ++j) v[j] = (bf16_t)tile[col + j][r];
    *(bf16x8_t*)&out[(size_t)(n0 + r) * K + k0 + col] = v;
  }
}

__global__ __launch_bounds__(256) void cast_kernel(const float* __restrict__ in,
                                                   bf16_t* __restrict__ out) {
  int i = blockIdx.x * 256 + threadIdx.x;
  f32x4_t a = ((const f32x4_t*)in)[i * 2];
  f32x4_t b = ((const f32x4_t*)in)[i * 2 + 1];
  bf16x8_t o;
#pragma unroll
  for (int j = 0; j < 4; ++j) { o[j] = (bf16_t)a[j]; o[4 + j] = (bf16_t)b[j]; }
  ((bf16x8_t*)out)[i] = o;
}

// ------- layer-0 aggregation, d=256 -------
__global__ __launch_bounds__(64) void agg0_kernel(const bf16_t* __restrict__ x,
                                                  bf16_t* __restrict__ out,
                                                  const int* __restrict__ rs,
                                                  const int* __restrict__ csr) {
  int t = threadIdx.x;
  int node = blockIdx.x * 2 + (t >> 5);
  int c = t & 31;
  const bf16x8_t* xv = (const bf16x8_t*)x;
  bf16x8_t self = xv[(size_t)node * 32 + c];
  float acc[8];
#pragma unroll
  for (int j = 0; j < 8; ++j) acc[j] = (float)self[j];
  int e0 = rs[node], e1 = rs[node + 1];
  int e = e0;
  for (; e + 4 <= e1; e += 4) {
    int s0 = csr[e], s1 = csr[e + 1], s2 = csr[e + 2], s3 = csr[e + 3];
    bf16x8_t v0 = xv[(size_t)s0 * 32 + c];
    bf16x8_t v1 = xv[(size_t)s1 * 32 + c];
    bf16x8_t v2 = xv[(size_t)s2 * 32 + c];
    bf16x8_t v3 = xv[(size_t)s3 * 32 + c];
#pragma unroll
    for (int j = 0; j < 8; ++j)
      acc[j] += (float)v0[j] + (float)v1[j] + (float)v2[j] + (float)v3[j];
  }
  for (; e < e1; ++e) {
    bf16x8_t v = xv[(size_t)csr[e] * 32 + c];
#pragma unroll
    for (int j = 0; j < 8; ++j) acc[j] += (float)v[j];
  }
  bf16x8_t o;
#pragma unroll
  for (int j = 0; j < 8; ++j) o[j] = (bf16_t)acc[j];
  ((bf16x8_t*)out)[(size_t)node * 32 + c] = o;
}

// ------- aggregation over tiled activations, XCD-pinned tiles (validated r8) -------
// (r5 form restored: r7's nt-store+8-unroll regressed -- AGG output is re-read as the
// next GEMM's A, so evicting it from L2 made the GEMM staging miss.)
__global__ __launch_bounds__(256) void agg_tiled_kernel(const bf16_t* __restrict__ x,
                                                        bf16_t* __restrict__ out,
                                                        const int* __restrict__ rs,
                                                        const int* __restrict__ csr,
                                                        const float* __restrict__ bias,
                                                        int relu, int tmask, int tshift) {
  int t = threadIdx.x;
  int tile = blockIdx.x & tmask;
  int ng = blockIdx.x >> tshift;
  int node = ng * 8 + (t >> 5);
  int c = t & 31;
  size_t tb = (size_t)tile * (NN * 32);
  const bf16x8_t* xv = (const bf16x8_t*)x + tb;
  bf16x8_t self = xv[node * 32 + c];
  float acc[8];
#pragma unroll
  for (int j = 0; j < 8; ++j) acc[j] = (float)self[j];
  int e0 = rs[node], e1 = rs[node + 1];
  int e = e0;
  for (; e + 4 <= e1; e += 4) {
    int s0 = csr[e], s1 = csr[e + 1], s2 = csr[e + 2], s3 = csr[e + 3];
    bf16x8_t v0 = xv[s0 * 32 + c];
    bf16x8_t v1 = xv[s1 * 32 + c];
    bf16x8_t v2 = xv[s2 * 32 + c];
    bf16x8_t v3 = xv[s3 * 32 + c];
#pragma unroll
    for (int j = 0; j < 8; ++j)
      acc[j] += (float)v0[j] + (float)v1[j] + (float)v2[j] + (float)v3[j];
  }
  for (; e < e1; ++e) {
    bf16x8_t v = xv[csr[e] * 32 + c];
#pragma unroll
    for (int j = 0; j < 8; ++j) acc[j] += (float)v[j];
  }
  if (bias) {
    const float* bp = bias + tile * 256 + c * 8;
    f32x4_t b0 = *(const f32x4_t*)bp;
    f32x4_t b1 = *(const f32x4_t*)(bp + 4);
#pragma unroll
    for (int j = 0; j < 4; ++j) { acc[j] += b0[j]; acc[4 + j] += b1[j]; }
  }
  if (relu) {
#pragma unroll
    for (int j = 0; j < 8; ++j) acc[j] = fmaxf(acc[j], 0.f);
  }
  bf16x8_t o;
#pragma unroll
  for (int j = 0; j < 8; ++j) o[j] = (bf16_t)acc[j];
  ((bf16x8_t*)out + tb)[node * 32 + c] = o;
}

// ------- OLD GEMM (128x128 tile): kept for N=1024 GEMMs and the heads GEMM -------
template <int CMODE>
__global__ __launch_bounds__(256, 2) void gemm_bt_kernel(
    const bf16_t* __restrict__ A, const bf16_t* __restrict__ Bt,
    const float* __restrict__ bias, const float* __restrict__ biasB,
    void* __restrict__ Cv, int N, int K, int relu, int nbxShift) {
  __shared__ __align__(16) bf16_t lA[128 * 32];
  __shared__ __align__(16) bf16_t lB[128 * 32];
  const int tid = threadIdx.x;
  const int lane = tid & 63;
  const int wave = tid >> 6;
  const int wm64 = (wave & 1) * 64;
  const int wn64 = (wave >> 1) * 64;
  const int row16 = lane & 15;
  const int quad = lane >> 4;

  const int bid = blockIdx.x;
  const int xcd = bid & 7;
  const int rank = bid >> 3;
  const int bn = rank & ((1 << nbxShift) - 1);
  const int mPer = gridDim.x >> (3 + nbxShift);
  const int bm = xcd * mPer + (rank >> nbxShift);
  const size_t m0 = (size_t)bm * 128;
  const size_t n0 = (size_t)bn * 128;

  f32x4_t acc[4][4];
#pragma unroll
  for (int i = 0; i < 4; ++i)
#pragma unroll
    for (int j = 0; j < 4; ++j)
#pragma unroll
      for (int r = 0; r < 4; ++r) acc[i][j][r] = 0.f;

  const bf16_t* Bbase = Bt + n0 * K;
  const int r0 = tid >> 2;
  const int r1 = (tid + 256) >> 2;
  const int kc = (tid & 3) * 8;

  for (int kt = 0; kt < K; kt += 32) {
    const bf16_t* Ab = A + ((size_t)(kt >> 8)) * (NN * 256) + (kt & 255) + kc;
    async16(&lA[tid * 8], Ab + (m0 + r0) * 256);
    async16(&lA[(tid + 256) * 8], Ab + (m0 + r1) * 256);
    async16(&lB[tid * 8], Bbase + (size_t)r0 * K + kt + kc);
    async16(&lB[(tid + 256) * 8], Bbase + (size_t)r1 * K + kt + kc);
    __syncthreads();
    bf16x8_t af[4], bfr[4];
#pragma unroll
    for (int i = 0; i < 4; ++i)
      af[i] = *(const bf16x8_t*)&lA[(wm64 + i * 16 + row16) * 32 + quad * 8];
#pragma unroll
    for (int i = 0; i < 4; ++i)
      bfr[i] = *(const bf16x8_t*)&lB[(wn64 + i * 16 + row16) * 32 + quad * 8];
#pragma unroll
    for (int i = 0; i < 4; ++i)
#pragma unroll
      for (int j = 0; j < 4; ++j)
        acc[i][j] = __builtin_amdgcn_mfma_f32_16x16x32_bf16(af[i], bfr[j], acc[i][j], 0, 0, 0);
    __syncthreads();
  }

  // C/D layout: col = lane&15, row = quad*4 + reg  [verified m89/m91]
#pragma unroll
  for (int i = 0; i < 4; ++i) {
    size_t row = m0 + wm64 + i * 16 + quad * 4;
#pragma unroll
    for (int j = 0; j < 4; ++j) {
      int col = (int)n0 + wn64 + j * 16 + row16;
      if (CMODE == 0) {
        float b = bias ? bias[col] : 0.f;
        size_t cb = ((size_t)(col >> 8)) * (NN * 256) + (col & 255);
#pragma unroll
        for (int r = 0; r < 4; ++r) {
          float o = acc[i][j][r] + b;
          if (relu) o = fmaxf(o, 0.f);
          ((bf16_t*)Cv)[cb + (row + r) * 256] = (bf16_t)o;
        }
      } else {
        int sel = col >> 7;
        int c2 = col & 127;
        float b = sel ? biasB[c2] : bias[c2];
        float* dstp = (float*)Cv + (size_t)(1 + sel) * NN * LL + c2;
#pragma unroll
        for (int r = 0; r < 4; ++r) {
          dstp[(row + r) * LL] = acc[i][j][r] + b;
        }
      }
    }
  }
}

// ------- NEW GEMM: 256x256 tile, BK=64, 8-wave. template<MERGED> within-probe A/B -------
// MERGED=0: r5 exact (best-known 71us): 4 phases/K-tile, 8 barriers, reads {12,4,8,0}.
// MERGED=1: same read/stage/vmcnt bookkeeping but quadrant pairs sharing an A-half are
//   merged into ONE barrier-pair: 2 phases/K-tile, 4 barriers, reads {16,8}, 32 MFMA per
//   phase. Tests the barrier-cost theory (R7 post-mortem: MFMA issue occupancy only ~12%;
//   LDS reads ruled out by r5's null; residual ~3300cyc/K-tile attributed to 8 barrier
//   crossings with only 2 waves/SIMD to hide arrival skew).
// Hazards (MERGED=1, re-derived): stages per tile: p0 issues A1(T+1),B1(T+1); p1 issues
// A0(T+2),B0(T+2). At p1's vmcnt(4): FIFO = [A0,B0(T+1) | A1,B1(T+1) | A0,B0(T+2)] = 12
// -> drains tile T+1 entirely, keeps A0/B0(T+2) in flight (never 0 in-loop). Reads of
// tile T+1 all occur after that drain + barrier. WAR: each restage is issued after the
// closing barrier of the phase whose MFMA (preceded by the compiler's counted lgkm wait)
// consumed that slot -- barrier arrival implies all waves' reads complete.
// LDS read swizzle elem^=(row&7)<<3; inverse pre-applied to the GLOBAL source so the
// global_load_lds dest stays linear (rule #21).
template <int MERGED>
__global__ __launch_bounds__(512, 2) void gemm256_kernel(
    const bf16_t* __restrict__ A, const bf16_t* __restrict__ Bt,
    const float* __restrict__ bias, bf16_t* __restrict__ C,
    int N, int K, int relu, int nbxShift) {
  __shared__ __align__(16) bf16_t lA[2][256 * 64];
  __shared__ __align__(16) bf16_t lB[2][256 * 64];

  const int t = threadIdx.x;
  const int lane = t & 63;
  const int wave = t >> 6;
  const int wm = wave >> 2;  // 0..1
  const int wn = wave & 3;   // 0..3
  const int row16 = lane & 15;
  const int quad = lane >> 4;
  const int sx = (row16 & 7) << 3;  // read-side swizzle XOR (elements)

  // staging constants: thread t covers rows r0 and r0+64 of a 128-row half, 8 elems each
  const int r0 = t >> 3;
  const int cs = ((t & 7) * 8) ^ ((r0 & 7) << 3);  // pre-swizzled source column (elements)

  const int bid = blockIdx.x;
  const int xcd = bid & 7;
  const int rank = bid >> 3;
  const int bn = rank & ((1 << nbxShift) - 1);
  const int mPer = gridDim.x >> (3 + nbxShift);
  const int bm = xcd * mPer + (rank >> nbxShift);
  const size_t m0 = (size_t)bm * 256;
  const size_t n0 = (size_t)bn * 256;
  const int NT = K >> 6;

  f32x4_t acc[4][4][2];
#pragma unroll
  for (int Q = 0; Q < 4; ++Q)
#pragma unroll
    for (int i = 0; i < 4; ++i)
#pragma unroll
      for (int j = 0; j < 2; ++j)
#pragma unroll
        for (int r = 0; r < 4; ++r) acc[Q][i][j][r] = 0.f;

  bf16x8_t af[4][2], bfA[2][2], bfB[2][2];

#define LOAD_A(mh)                                                                 \
  _Pragma("unroll") for (int i = 0; i < 4; ++i)                                    \
  _Pragma("unroll") for (int ks = 0; ks < 2; ++ks) {                               \
    int row_ = (mh)*128 + wm * 64 + i * 16 + row16;                                \
    af[i][ks] = *(const bf16x8_t*)&lA[c][row_ * 64 + ((ks * 32 + quad * 8) ^ sx)]; \
  }

#define LOAD_B(dstv, nh)                                                             \
  _Pragma("unroll") for (int j = 0; j < 2; ++j)                                      \
  _Pragma("unroll") for (int ks = 0; ks < 2; ++ks) {                                 \
    int row_ = (nh)*128 + wn * 32 + j * 16 + row16;                                  \
    dstv[j][ks] = *(const bf16x8_t*)&lB[c][row_ * 64 + ((ks * 32 + quad * 8) ^ sx)]; \
  }

#define STAGE_A256(U, mh)                                                            \
  {                                                                                  \
    int u_ = (U);                                                                    \
    int us_ = u_ < NT ? u_ : NT - 1;                                                 \
    int kt_ = us_ << 6;                                                              \
    const bf16_t* g_ = A + (size_t)(kt_ >> 8) * (NN * 256) + (m0 + (mh)*128) * 256 + \
                       (kt_ & 255) + cs;                                             \
    bf16_t* l_ = &lA[u_ & 1][(mh)*8192];                                             \
    async16(l_ + (size_t)t * 8, g_ + (size_t)r0 * 256);                              \
    async16(l_ + (size_t)(t + 512) * 8, g_ + (size_t)(r0 + 64) * 256);               \
  }

#define STAGE_B256(U, nh)                                                  \
  {                                                                        \
    int u_ = (U);                                                          \
    int us_ = u_ < NT ? u_ : NT - 1;                                       \
    int kt_ = us_ << 6;                                                    \
    const bf16_t* g_ = Bt + (n0 + (nh)*128) * (size_t)K + kt_ + cs;        \
    bf16_t* l_ = &lB[u_ & 1][(nh)*8192];                                   \
    async16(l_ + (size_t)t * 8, g_ + (size_t)r0 * K);                      \
    async16(l_ + (size_t)(t + 512) * 8, g_ + (size_t)(r0 + 64) * K);       \
  }

#define MFMA_Q(Q, BFX)                                                               \
  __builtin_amdgcn_s_setprio(1);                                                     \
  _Pragma("unroll") for (int i = 0; i < 4; ++i)                                      \
  _Pragma("unroll") for (int j = 0; j < 2; ++j)                                      \
  _Pragma("unroll") for (int ks = 0; ks < 2; ++ks)                                   \
      acc[Q][i][j] = __builtin_amdgcn_mfma_f32_16x16x32_bf16(                        \
          af[i][ks], BFX[j][ks], acc[Q][i][j], 0, 0, 0);                             \
  __builtin_amdgcn_s_setprio(0);

#define BAR asm volatile("s_barrier" ::: "memory")

  // Prologue: tile0 (4 halves) + A0/B0 of tile1. Fence pins issue order so
  // vmcnt(4) drains exactly tile0's 8 loads, leaving A0/B0(1) in flight.
  STAGE_A256(0, 0); STAGE_B256(0, 0); STAGE_A256(0, 1); STAGE_B256(0, 1);
  asm volatile("" ::: "memory");
  STAGE_A256(1, 0); STAGE_B256(1, 0);
  asm volatile("s_waitcnt vmcnt(4)" ::: "memory");
  BAR;

  for (int T = 0; T < NT; ++T) {
    const int c = T & 1;
    if (MERGED == 0) {
      // q0: (0,0) -- 12 reads
      LOAD_A(0);
      LOAD_B(bfA, 0);
      STAGE_A256(T + 1, 1);
      asm volatile("s_waitcnt lgkmcnt(8)" ::: "memory");
      BAR;
      MFMA_Q(0, bfA);
      BAR;
      // q1: (0,1) -- 4 reads
      LOAD_B(bfB, 1);
      STAGE_B256(T + 1, 1);
      BAR;
      MFMA_Q(1, bfB);
      BAR;
      // q2: (1,0) -- 8 reads (B persistent in bfA)
      LOAD_A(1);
      STAGE_A256(T + 2, 0);
      BAR;
      MFMA_Q(2, bfA);
      BAR;
      // q3: (1,1) -- 0 reads (B persistent in bfB)
      STAGE_B256(T + 2, 0);
      BAR;
      MFMA_Q(3, bfB);
      asm volatile("s_waitcnt vmcnt(4)" ::: "memory");
      BAR;
    } else {
      // p0: quadrants (0,0)+(0,1) share af(mh=0) -- 16 reads, 32 MFMA
      LOAD_A(0);
      LOAD_B(bfA, 0);
      LOAD_B(bfB, 1);
      STAGE_A256(T + 1, 1);
      STAGE_B256(T + 1, 1);
      asm volatile("s_waitcnt lgkmcnt(8)" ::: "memory");
      BAR;
      MFMA_Q(0, bfA);
      MFMA_Q(1, bfB);
      BAR;
      // p1: quadrants (1,0)+(1,1) share af(mh=1) -- 8 reads, 32 MFMA
      LOAD_A(1);
      STAGE_A256(T + 2, 0);
      STAGE_B256(T + 2, 0);
      BAR;
      MFMA_Q(2, bfA);
      MFMA_Q(3, bfB);
      asm volatile("s_waitcnt vmcnt(4)" ::: "memory");
      BAR;
    }
  }
  asm volatile("s_waitcnt vmcnt(0)" ::: "memory");

  // Epilogue: C/D layout col = lane&15, row = quad*4 + reg [verified m89/m91]
#pragma unroll
  for (int Q = 0; Q < 4; ++Q) {
    const int mh = Q >> 1, nh = Q & 1;
#pragma unroll
    for (int i = 0; i < 4; ++i) {
      size_t row = m0 + mh * 128 + wm * 64 + i * 16 + quad * 4;
#pragma unroll
      for (int j = 0; j < 2; ++j) {
        int col = (int)n0 + nh * 128 + wn * 32 + j * 16 + row16;
        float b = bias ? bias[col] : 0.f;
        size_t cb = ((size_t)(col >> 8)) * (NN * 256) + (col & 255);
#pragma unroll
        for (int r = 0; r < 4; ++r) {
          float o = acc[Q][i][j][r] + b;
          if (relu) o = fmaxf(o, 0.f);
          C[cb + (row + r) * 256] = (bf16_t)o;
        }
      }
    }
  }
#undef LOAD_A
#undef LOAD_B
#undef STAGE_A256
#undef STAGE_B256
#undef MFMA_Q
#undef BAR
}

// ---------------- z = mean + var*eps (f32) ----------------
__global__ __launch_bounds__(256) void reparam_kernel(const float* __restrict__ mean,
                                                      const float* __restrict__ var,
                                                      const float* __restrict__ eps,
                                                      float* __restrict__ z) {
  int i = blockIdx.x * 256 + threadIdx.x;
  f32x4_t m = ((const f32x4_t*)mean)[i];
  f32x4_t v = ((const f32x4_t*)var)[i];
  f32x4_t e = ((const f32x4_t*)eps)[i];
  f32x4_t o;
#pragma unroll
  for (int j = 0; j < 4; ++j) o[j] = m[j] + v[j] * e[j];
  ((f32x4_t*)z)[i] = o;
}

extern "C" void kernel_launch(void* const* d_in, const int* in_sizes, int n_in,
                              void* d_out, int out_size, void* d_ws, size_t ws_size,
                              hipStream_t stream) {
  (void)in_sizes; (void)n_in; (void)out_size;
  const float* x0 = (const float*)d_in[0];
  const int* ei = (const int*)d_in[1];
  const int* src = ei;
  const int* dst = ei + EE;
  const float* w1[4] = {(const float*)d_in[2], (const float*)d_in[6],
                        (const float*)d_in[10], (const float*)d_in[14]};
  const float* b1[4] = {(const float*)d_in[3], (const float*)d_in[7],
                        (const float*)d_in[11], (const float*)d_in[15]};
  const float* w2[4] = {(const float*)d_in[4], (const float*)d_in[8],
                        (const float*)d_in[12], (const float*)d_in[16]};
  const float* b2[4] = {(const float*)d_in[5], (const float*)d_in[9],
                        (const float*)d_in[13], (const float*)d_in[17]};
  const float* wm = (const float*)d_in[18];
  const float* bm = (const float*)d_in[19];
  const float* wv = (const float*)d_in[20];
  const float* bv = (const float*)d_in[21];
  const float* eps = (const float*)d_in[22];
  float* out = (float*)d_out;

  char* ws = (char*)d_ws;
  bf16_t* B0 = (bf16_t*)(ws);
  bf16_t* B1 = (bf16_t*)(ws + 33554432);
  bf16_t* WT = (bf16_t*)(ws + 67108864);

  // Per-weight WT slot offsets (bf16 elems), order: w1_0,w2_0,w1_1,w2_1,w1_2,w2_2,w1_3,w2_3,wm,wv
  const long long soff[NW] = {0LL, 524288LL, 4718592LL, 8912896LL, 13107200LL,
                              17301504LL, 21495808LL, 23592960LL, 24641536LL, 24772608LL};
  const size_t wtBytesFull = 24903680ULL * 2ULL;          // 49.8 MB
  const size_t needFull = 67108864ULL + wtBytesFull + 2097152ULL;
  bool full = ws_size >= needFull;

  size_t csrBase = full ? (67108864ULL + wtBytesFull) : 75497472ULL;
  int* deg = (int*)(ws + csrBase);
  int* cur = deg + 8192;
  int* rs = deg + 16384;
  int* csr = deg + 16384 + 8200;

  auto AGG = [&](const bf16_t* in, bf16_t* outp, int d, const float* bias, int relu) {
    int ntiles = d >> 8;
    int tshift = (ntiles == 8) ? 3 : 2;
    agg_tiled_kernel<<<(NN / 8) * ntiles, 256, 0, stream>>>(in, outp, rs, csr, bias, relu,
                                                            ntiles - 1, tshift);
  };

  if (full) {
    // ---- merged prep: all transposes + x0 cast in one dispatch ----
    WTab tab;
    const float* srcs[NW] = {w1[0], w2[0], w1[1], w2[1], w1[2], w2[2], w1[3], w2[3], wm, wv};
    const int Ks[NW] = {TT, HH, HH, HH, HH, HH, HH, OO, OO, OO};
    const int Ns[NW] = {HH, HH, HH, HH, HH, HH, OO, OO, LL, LL};
    int cum = 0;
    for (int i = 0; i < NW; ++i) {
      tab.src[i] = srcs[i];
      tab.K[i] = Ks[i];
      tab.N[i] = Ns[i];
      tab.dstOff[i] = soff[i];
      tab.tileStart[i] = cum;
      cum += (Ns[i] >> 6) * (Ks[i] >> 6);
    }
    tab.tileStart[NW] = cum;
    tab.castStart = cum;
    tab.x0 = x0;
    tab.castDst = B0;
    int totalBlocks = cum + (NN * TT / 8) / 256;
    prep_all_kernel<<<totalBlocks, 256, 0, stream>>>(tab, WT);

    hipMemsetAsync(deg, 0, 2 * 8192 * sizeof(int), stream);
    count_deg_kernel<<<EE / 256, 256, 0, stream>>>(dst, deg);
    scan_kernel<<<1, 1024, 0, stream>>>(deg, rs);
    fill_csr_kernel<<<EE / 256, 256, 0, stream>>>(src, dst, rs, cur, csr);

    // N=2048 GEMMs: within-probe A/B -- MERGED=0 (r5) on layers 2,4; MERGED=1 on 0,1,3,5
    auto G2a = [&](const bf16_t* Ain, int wi, const float* bias, bf16_t* Cout, int K,
                   int relu) {
      gemm256_kernel<0><<<8 * (NN / 256), 512, 0, stream>>>(Ain, WT + soff[wi], bias, Cout,
                                                            HH, K, relu, 3);
    };
    auto G2b = [&](const bf16_t* Ain, int wi, const float* bias, bf16_t* Cout, int K,
                   int relu) {
      gemm256_kernel<1><<<8 * (NN / 256), 512, 0, stream>>>(Ain, WT + soff[wi], bias, Cout,
                                                            HH, K, relu, 3);
    };
    // N=1024 GEMMs stay on the 128^2 kernel
    auto G = [&](const bf16_t* Ain, int wi, const float* bias, bf16_t* Cout, int Nn, int K,
                 int relu) {
      int nbx = Nn / 128;
      int shift = __builtin_ctz(nbx);
      gemm_bt_kernel<0><<<nbx * (NN / 128), 256, 0, stream>>>(
          Ain, WT + soff[wi], bias, nullptr, (void*)Cout, Nn, K, relu, shift);
    };

    agg0_kernel<<<NN / 2, 64, 0, stream>>>(B0, B1, rs, csr);
    G2b(B1, 0, b1[0], B0, TT, 1);
    G2b(B0, 1, b2[0], B1, HH, 1);
    AGG(B1, B0, HH, nullptr, 0);
    G2a(B0, 2, b1[1], B1, HH, 1);
    G2b(B1, 3, b2[1], B0, HH, 1);
    AGG(B0, B1, HH, nullptr, 0);
    G2a(B1, 4, b1[2], B0, HH, 1);
    G2b(B0, 5, b2[2], B1, HH, 1);
    // Layer 3 reordered: Y = x3 @ w1_3 (no bias); agg 1024-d fused b1_3+relu; then w2_3.
    G(B1, 6, nullptr, B0, OO, HH, 0);
    AGG(B0, B1, OO, b1[3], 1);
    G(B1, 7, b2[3], B0, OO, OO, 0);
    // Heads: wm|wv adjacent -> one N=256 GEMM, f32 split epilogue, direct bm/bv
    gemm_bt_kernel<1><<<2 * (NN / 128), 256, 0, stream>>>(
        B0, WT + soff[8], bm, bv, (void*)out, 256, OO, 0, 1);
  } else {
    // ---- fallback: interleaved scheme (shared 8.4MB WT) ----
    hipMemsetAsync(deg, 0, 2 * 8192 * sizeof(int), stream);
    count_deg_kernel<<<EE / 256, 256, 0, stream>>>(dst, deg);
    scan_kernel<<<1, 1024, 0, stream>>>(deg, rs);
    fill_csr_kernel<<<EE / 256, 256, 0, stream>>>(src, dst, rs, cur, csr);

    auto T = [&](const float* w, int K, int Nn, bf16_t* dstw) {
      transpose_cast_kernel<<<dim3(Nn / 64, K / 64), 256, 0, stream>>>(w, dstw, K, Nn);
    };
    auto G2 = [&](const bf16_t* Ain, const float* bias, bf16_t* Cout, int K, int relu) {
      gemm256_kernel<0><<<8 * (NN / 256), 512, 0, stream>>>(Ain, WT, bias, Cout, HH, K,
                                                            relu, 3);
    };
    auto G = [&](const bf16_t* Ain, const float* bias, bf16_t* Cout, int Nn, int K, int relu) {
      int nbx = Nn / 128;
      int shift = __builtin_ctz(nbx);
      gemm_bt_kernel<0><<<nbx * (NN / 128), 256, 0, stream>>>(
          Ain, WT, bias, nullptr, (void*)Cout, Nn, K, relu, shift);
    };

    cast_kernel<<<(NN * TT / 8) / 256, 256, 0, stream>>>(x0, B0);
    agg0_kernel<<<NN / 2, 64, 0, stream>>>(B0, B1, rs, csr);
    T(w1[0], TT, HH, WT); G2(B1, b1[0], B0, TT, 1);
    T(w2[0], HH, HH, WT); G2(B0, b2[0], B1, HH, 1);
    AGG(B1, B0, HH, nullptr, 0);
    T(w1[1], HH, HH, WT); G2(B0, b1[1], B1, HH, 1);
    T(w2[1], HH, HH, WT); G2(B1, b2[1], B0, HH, 1);
    AGG(B0, B1, HH, nullptr, 0);
    T(w1[2], HH, HH, WT); G2(B1, b1[2], B0, HH, 1);
    T(w2[2], HH, HH, WT); G2(B0, b2[2], B1, HH, 1);
    T(w1[3], HH, OO, WT); G(B1, nullptr, B0, OO, HH, 0);
    AGG(B0, B1, OO, b1[3], 1);
    T(w2[3], OO, OO, WT); G(B1, b2[3], B0, OO, OO, 0);
    T(wm, OO, LL, WT);
    T(wv, OO, LL, WT + (size_t)LL * OO);
    gemm_bt_kernel<1><<<2 * (NN / 128), 256, 0, stream>>>(
        B0, WT, bm, bv, (void*)out, 256, OO, 0, 1);
  }

  reparam_kernel<<<(NN * LL / 4) / 256, 256, 0, stream>>>(
      out + (size_t)NN * LL, out + (size_t)2 * NN * LL, eps, out);
}